// Round 6
// baseline (567.297 us; speedup 1.0000x reference)
//
#include <hip/hip_runtime.h>
#include <math.h>

// R5: kill the gather-latency serial loops.
//   - agg_x / agg2pool: wave per node, 64 lanes = 4 edge-streams x 16 lanes x 8
//     features -> 4 independent gather chains per thread, folded by shfl_xor(16,32).
//   - per-edge exp precomputed edge-parallel (ex1[E,8], ex2[E]); agg loops read it
//     sequentially. No exp / score-gather in the hot loops.
//   - fill_edges additionally records dsts[p] for the exp kernels.

#define NEG_SLOPE 0.2f

using bf16x8 = __attribute__((ext_vector_type(8))) __bf16;
using f32x4  = __attribute__((ext_vector_type(4))) float;

// ---------- bf16 helpers ----------
__device__ __forceinline__ ushort f2bf(float f) {
    unsigned u = __float_as_uint(f);
    unsigned r = (u + 0x7FFFu + ((u >> 16) & 1u)) >> 16;   // RNE
    return (ushort)r;
}
__device__ __forceinline__ unsigned pack2(float a, float b) {
    return (unsigned)f2bf(a) | ((unsigned)f2bf(b) << 16);
}
__device__ __forceinline__ void unpack8(uint4 u, float* f) {
    f[0] = __uint_as_float(u.x << 16); f[1] = __uint_as_float(u.x & 0xFFFF0000u);
    f[2] = __uint_as_float(u.y << 16); f[3] = __uint_as_float(u.y & 0xFFFF0000u);
    f[4] = __uint_as_float(u.z << 16); f[5] = __uint_as_float(u.z & 0xFFFF0000u);
    f[6] = __uint_as_float(u.w << 16); f[7] = __uint_as_float(u.w & 0xFFFF0000u);
}

__device__ __forceinline__ float leaky(float e) {
    return e > 0.f ? e : NEG_SLOPE * e;
}

// ---------------- fp32 -> bf16 convert ----------------
__global__ __launch_bounds__(256) void cvt_bf16(const float* __restrict__ in,
                                                ushort* __restrict__ out, int n4) {
    int i = blockIdx.x * 256 + threadIdx.x;
    if (i >= n4) return;
    float4 v = ((const float4*)in)[i];
    uint2 o;
    o.x = pack2(v.x, v.y);
    o.y = pack2(v.z, v.w);
    ((uint2*)out)[i] = o;
}

// ---------------- prep: v_s/v_d[h,f] = sum_c att[h,c] * W1[h*64+c, f] ----------
__global__ __launch_bounds__(256) void prep_v(const float* __restrict__ W1,
                                              const float* __restrict__ att_s,
                                              const float* __restrict__ att_d,
                                              float* __restrict__ v_s,
                                              float* __restrict__ v_d) {
    int tid = blockIdx.x * 256 + threadIdx.x;   // 1024 total
    int h = tid >> 7, f = tid & 127;
    float as = 0.f, ad = 0.f;
    for (int c = 0; c < 64; ++c) {
        float w = W1[(size_t)(h * 64 + c) * 128 + f];
        as += att_s[h * 64 + c] * w;
        ad += att_d[h * 64 + c] * w;
    }
    v_s[tid] = as;
    v_d[tid] = ad;
}

// ---------------- layer-1 scores from x: a1s/a1d [N,8] ----------------
__global__ __launch_bounds__(256) void scoresA(const ushort* __restrict__ xb,
                                               const float* __restrict__ v_s,
                                               const float* __restrict__ v_d,
                                               float* __restrict__ a1s,
                                               float* __restrict__ a1d, int N) {
    int node = blockIdx.x * 4 + (threadIdx.x >> 6);
    if (node >= N) return;
    int lane = threadIdx.x & 63;
    int head = lane >> 3, f0 = (lane & 7) * 16;
    const uint4* xp = (const uint4*)(xb + (size_t)node * 128 + f0);
    float xv[16];
    unpack8(xp[0], xv);
    unpack8(xp[1], xv + 8);
    const float4* sp = (const float4*)(v_s + head * 128 + f0);
    const float4* dp = (const float4*)(v_d + head * 128 + f0);
    float ps = 0.f, pd = 0.f;
#pragma unroll
    for (int q = 0; q < 4; ++q) {
        float4 s4 = sp[q], d4 = dp[q];
        ps += xv[q*4+0]*s4.x + xv[q*4+1]*s4.y + xv[q*4+2]*s4.z + xv[q*4+3]*s4.w;
        pd += xv[q*4+0]*d4.x + xv[q*4+1]*d4.y + xv[q*4+2]*d4.z + xv[q*4+3]*d4.w;
    }
#pragma unroll
    for (int off = 1; off < 8; off <<= 1) {
        ps += __shfl_xor(ps, off);
        pd += __shfl_xor(pd, off);
    }
    if ((lane & 7) == 0) {
        a1s[node * 8 + head] = ps;
        a1d[node * 8 + head] = pd;
    }
}

// ---------------- CSR build ----------------
__global__ void count_edges(const int* __restrict__ dst, int* cnt, int E) {
    int e = blockIdx.x * 256 + threadIdx.x;
    if (e < E) atomicAdd(&cnt[dst[e]], 1);
}

__global__ __launch_bounds__(1024) void scan_offsets(const int* cnt, int* row_start,
                                                     int* cursor, int N) {
    __shared__ int sm[1024];
    int t = threadIdx.x;
    int per = (N + 1023) / 1024;
    int beg = t * per;
    int end = beg + per; if (end > N) end = N;
    int sum = 0;
    for (int i = beg; i < end; ++i) sum += cnt[i];
    sm[t] = sum;
    __syncthreads();
    for (int off = 1; off < 1024; off <<= 1) {
        int add = (t >= off) ? sm[t - off] : 0;
        __syncthreads();
        sm[t] += add;
        __syncthreads();
    }
    int run = sm[t] - sum;
    for (int i = beg; i < end; ++i) {
        int c = cnt[i];
        row_start[i] = run;
        cursor[i] = run;
        run += c;
    }
    if (t == 1023) row_start[N] = run;
}

__global__ void fill_edges(const int* __restrict__ src, const int* __restrict__ dst,
                           int* cursor, int* __restrict__ srcs,
                           int* __restrict__ dsts, int E) {
    int e = blockIdx.x * 256 + threadIdx.x;
    if (e < E) {
        int d = dst[e];
        int pos = atomicAdd(&cursor[d], 1);
        srcs[pos] = src[e];
        dsts[pos] = d;
    }
}

// ---------------- per-edge exp, layer 1: ex1[p,8] ----------------
__global__ __launch_bounds__(256) void exp_edges1(const int* __restrict__ srcs,
                                                  const int* __restrict__ dsts,
                                                  const float* __restrict__ a1s,
                                                  const float* __restrict__ a1d,
                                                  float* __restrict__ ex1, int E) {
    int p = blockIdx.x * 256 + threadIdx.x;
    if (p >= E) return;
    int s = srcs[p], d = dsts[p];
    const float4* sp = (const float4*)(a1s + s * 8);
    const float4* dp = (const float4*)(a1d + d * 8);
    float4 s0 = sp[0], s1 = sp[1], d0 = dp[0], d1 = dp[1];
    float4 o0, o1;
    o0.x = __expf(leaky(s0.x + d0.x));
    o0.y = __expf(leaky(s0.y + d0.y));
    o0.z = __expf(leaky(s0.z + d0.z));
    o0.w = __expf(leaky(s0.w + d0.w));
    o1.x = __expf(leaky(s1.x + d1.x));
    o1.y = __expf(leaky(s1.y + d1.y));
    o1.z = __expf(leaky(s1.z + d1.z));
    o1.w = __expf(leaky(s1.w + d1.w));
    float4* op = (float4*)(ex1 + (size_t)p * 8);
    op[0] = o0; op[1] = o1;
}

// ---------------- per-edge exp, layer 2: ex2[p] ----------------
__global__ __launch_bounds__(256) void exp_edges2(const int* __restrict__ srcs,
                                                  const int* __restrict__ dsts,
                                                  const float* __restrict__ a2s,
                                                  const float* __restrict__ a2d,
                                                  float* __restrict__ ex2, int E) {
    int p = blockIdx.x * 256 + threadIdx.x;
    if (p >= E) return;
    ex2[p] = __expf(leaky(a2s[srcs[p]] + a2d[dsts[p]]));
}

// ---------------- layer-1 aggregate in x-space: ax[N,8,128] bf16 ----------------
// wave per node; 64 lanes = 4 edge-streams (eg) x 16 lanes (fl), 8 features/lane.
// acc[8 heads][8 feats] per lane; fold streams with shfl_xor(16,32) at the end.
__global__ __launch_bounds__(256) void agg_x(const ushort* __restrict__ xb,
                                             const float* __restrict__ a1s,
                                             const float* __restrict__ a1d,
                                             const int* __restrict__ row_start,
                                             const int* __restrict__ srcs,
                                             const float* __restrict__ ex1,
                                             ushort* __restrict__ ax, int N) {
    int node = blockIdx.x * 4 + (threadIdx.x >> 6);
    if (node >= N) return;
    int lane = threadIdx.x & 63;
    int eg = lane >> 4, fl = lane & 15;
    int f0 = fl * 8;
    int pbeg = row_start[node], pend = row_start[node + 1];
    float acc[8][8] = {};
    float den[8] = {};
    for (int p = pbeg + eg; p < pend; p += 4) {
        int s = srcs[p];
        const float4* ep = (const float4*)(ex1 + (size_t)p * 8);
        float4 e0 = ep[0], e1 = ep[1];
        float ex[8] = {e0.x, e0.y, e0.z, e0.w, e1.x, e1.y, e1.z, e1.w};
        float xv[8];
        unpack8(*(const uint4*)(xb + (size_t)s * 128 + f0), xv);
#pragma unroll
        for (int h = 0; h < 8; ++h) {
            den[h] += ex[h];
#pragma unroll
            for (int j = 0; j < 8; ++j) acc[h][j] += ex[h] * xv[j];
        }
    }
    // fold 4 edge streams
#pragma unroll
    for (int h = 0; h < 8; ++h) {
        den[h] += __shfl_xor(den[h], 16);
        den[h] += __shfl_xor(den[h], 32);
#pragma unroll
        for (int j = 0; j < 8; ++j) {
            acc[h][j] += __shfl_xor(acc[h][j], 16);
            acc[h][j] += __shfl_xor(acc[h][j], 32);
        }
    }
    // self loop (added once per lane, post-fold; all lanes hold folded totals)
    {
        const float4* sp = (const float4*)(a1s + node * 8);
        const float4* dp = (const float4*)(a1d + node * 8);
        float4 s0 = sp[0], s1 = sp[1], d0 = dp[0], d1 = dp[1];
        float exs[8];
        exs[0] = __expf(leaky(s0.x + d0.x));
        exs[1] = __expf(leaky(s0.y + d0.y));
        exs[2] = __expf(leaky(s0.z + d0.z));
        exs[3] = __expf(leaky(s0.w + d0.w));
        exs[4] = __expf(leaky(s1.x + d1.x));
        exs[5] = __expf(leaky(s1.y + d1.y));
        exs[6] = __expf(leaky(s1.z + d1.z));
        exs[7] = __expf(leaky(s1.w + d1.w));
        float xv[8];
        unpack8(*(const uint4*)(xb + (size_t)node * 128 + f0), xv);
#pragma unroll
        for (int h = 0; h < 8; ++h) {
            den[h] += exs[h];
#pragma unroll
            for (int j = 0; j < 8; ++j) acc[h][j] += exs[h] * xv[j];
        }
    }
    // store heads 2*eg, 2*eg+1 (every group holds identical folded data)
#pragma unroll
    for (int hh = 0; hh < 2; ++hh) {
        int h = eg * 2 + hh;
        float rden = 1.0f / (den[h] + 1e-16f);
        uint4 o;
        o.x = pack2(acc[h][0] * rden, acc[h][1] * rden);
        o.y = pack2(acc[h][2] * rden, acc[h][3] * rden);
        o.z = pack2(acc[h][4] * rden, acc[h][5] * rden);
        o.w = pack2(acc[h][6] * rden, acc[h][7] * rden);
        *(uint4*)(ax + (size_t)node * 1024 + h * 128 + f0) = o;
    }
}

// ---------------- grouped GEMM: r1[n, h*64+c] = relu(ax[n,h,:]@W1_h^T + b1) ----
#define LDSB 40
__global__ __launch_bounds__(256) void gemm_grouped(const ushort* __restrict__ AX,
                                                    const ushort* __restrict__ W1b,
                                                    const float* __restrict__ b1,
                                                    ushort* __restrict__ r1,
                                                    int M) {
    __shared__ ushort As[2][128 * LDSB];
    __shared__ ushort Bs[128 * LDSB];
    int t = threadIdx.x;
    int wave = t >> 6, lane = t & 63;
    int quad = lane >> 4, l16 = lane & 15;
    int m0 = blockIdx.x * 128;
    int y = blockIdx.y;                 // cols [128y, 128y+128), heads 2y, 2y+1
    int wm = (wave & 1) * 64;
    int wn = (wave >> 1) * 64;
    int hsel = wn >> 6;
    int srow = t >> 1;
    int sseg = (t & 1) * 16;
    f32x4 acc[4][4] = {};
    for (int k0 = 0; k0 < 128; k0 += 32) {
        uint4 a0v0, a0v1, a1v0, a1v1, bv0, bv1;
        {
            int grow = m0 + srow;
            if (grow < M) {
                const uint4* g0 = (const uint4*)(AX + (size_t)grow * 1024 + (2 * y) * 128 + k0 + sseg);
                const uint4* g1 = (const uint4*)(AX + (size_t)grow * 1024 + (2 * y + 1) * 128 + k0 + sseg);
                a0v0 = g0[0]; a0v1 = g0[1];
                a1v0 = g1[0]; a1v1 = g1[1];
            } else {
                a0v0 = make_uint4(0, 0, 0, 0); a0v1 = a0v0; a1v0 = a0v0; a1v1 = a0v0;
            }
            const uint4* gq = (const uint4*)(W1b + (size_t)(y * 128 + srow) * 128 + k0 + sseg);
            bv0 = gq[0]; bv1 = gq[1];
        }
        __syncthreads();
        *(uint4*)&As[0][srow * LDSB + sseg]     = a0v0;
        *(uint4*)&As[0][srow * LDSB + sseg + 8] = a0v1;
        *(uint4*)&As[1][srow * LDSB + sseg]     = a1v0;
        *(uint4*)&As[1][srow * LDSB + sseg + 8] = a1v1;
        *(uint4*)&Bs[srow * LDSB + sseg]        = bv0;
        *(uint4*)&Bs[srow * LDSB + sseg + 8]    = bv1;
        __syncthreads();
        bf16x8 af[4], bf[4];
#pragma unroll
        for (int i = 0; i < 4; ++i)
            af[i] = *(const bf16x8*)&As[hsel][(wm + i * 16 + l16) * LDSB + quad * 8];
#pragma unroll
        for (int j = 0; j < 4; ++j)
            bf[j] = *(const bf16x8*)&Bs[(wn + j * 16 + l16) * LDSB + quad * 8];
#pragma unroll
        for (int i = 0; i < 4; ++i)
#pragma unroll
            for (int j = 0; j < 4; ++j)
                acc[i][j] = __builtin_amdgcn_mfma_f32_16x16x32_bf16(
                    af[i], bf[j], acc[i][j], 0, 0, 0);
    }
#pragma unroll
    for (int i = 0; i < 4; ++i) {
#pragma unroll
        for (int r = 0; r < 4; ++r) {
            int grow = m0 + wm + i * 16 + quad * 4 + r;
            if (grow < M) {
#pragma unroll
                for (int j = 0; j < 4; ++j) {
                    int gcol = y * 128 + wn + j * 16 + l16;
                    float v = fmaxf(acc[i][j][r] + b1[gcol], 0.f);
                    r1[(size_t)grow * 512 + gcol] = f2bf(v);
                }
            }
        }
    }
}

// ---------------- MFMA GEMM (layer 2): C[M,N] = A[M,K]*B[N,K]^T, bf16 ----------
__global__ __launch_bounds__(256) void gemm_mfma(const ushort* __restrict__ A,
                                                 const ushort* __restrict__ B,
                                                 ushort* __restrict__ C,
                                                 int M, int N, int K) {
    __shared__ ushort As[128 * LDSB];
    __shared__ ushort Bs[128 * LDSB];
    int t = threadIdx.x;
    int wave = t >> 6, lane = t & 63;
    int quad = lane >> 4, l16 = lane & 15;
    int m0 = blockIdx.x * 128;
    int n0 = blockIdx.y * 128;
    int wm = (wave & 1) * 64;
    int wn = (wave >> 1) * 64;
    int srow = t >> 1;
    int sseg = (t & 1) * 16;
    f32x4 acc[4][4] = {};
    for (int k0 = 0; k0 < K; k0 += 32) {
        uint4 av0, av1, bv0, bv1;
        {
            int grow = m0 + srow;
            if (grow < M) {
                const uint4* gp = (const uint4*)(A + (size_t)grow * K + k0 + sseg);
                av0 = gp[0]; av1 = gp[1];
            } else {
                av0 = make_uint4(0, 0, 0, 0); av1 = av0;
            }
            const uint4* gq = (const uint4*)(B + (size_t)(n0 + srow) * K + k0 + sseg);
            bv0 = gq[0]; bv1 = gq[1];
        }
        __syncthreads();
        *(uint4*)&As[srow * LDSB + sseg]     = av0;
        *(uint4*)&As[srow * LDSB + sseg + 8] = av1;
        *(uint4*)&Bs[srow * LDSB + sseg]     = bv0;
        *(uint4*)&Bs[srow * LDSB + sseg + 8] = bv1;
        __syncthreads();
        bf16x8 af[4], bf[4];
#pragma unroll
        for (int i = 0; i < 4; ++i)
            af[i] = *(const bf16x8*)&As[(wm + i * 16 + l16) * LDSB + quad * 8];
#pragma unroll
        for (int j = 0; j < 4; ++j)
            bf[j] = *(const bf16x8*)&Bs[(wn + j * 16 + l16) * LDSB + quad * 8];
#pragma unroll
        for (int i = 0; i < 4; ++i)
#pragma unroll
            for (int j = 0; j < 4; ++j)
                acc[i][j] = __builtin_amdgcn_mfma_f32_16x16x32_bf16(
                    af[i], bf[j], acc[i][j], 0, 0, 0);
    }
#pragma unroll
    for (int i = 0; i < 4; ++i) {
#pragma unroll
        for (int r = 0; r < 4; ++r) {
            int grow = m0 + wm + i * 16 + quad * 4 + r;
            if (grow < M) {
#pragma unroll
                for (int j = 0; j < 4; ++j) {
                    int gcol = n0 + wn + j * 16 + l16;
                    C[(size_t)grow * N + gcol] = f2bf(acc[i][j][r]);
                }
            }
        }
    }
}

// ---------------- layer-2 scores ----------------
__global__ __launch_bounds__(256) void scores2(const ushort* __restrict__ h2,
                                               const float* __restrict__ att_s,
                                               const float* __restrict__ att_d,
                                               float* __restrict__ a2s,
                                               float* __restrict__ a2d, int N) {
    int node = blockIdx.x * 4 + (threadIdx.x >> 6);
    if (node >= N) return;
    int lane = threadIdx.x & 63;
    unsigned u = *(const unsigned*)(h2 + (size_t)node * 128 + lane * 2);
    float h0 = __uint_as_float(u << 16), h1v = __uint_as_float(u & 0xFFFF0000u);
    float2 s = *(const float2*)(att_s + lane * 2);
    float2 d = *(const float2*)(att_d + lane * 2);
    float ps = h0 * s.x + h1v * s.y;
    float pd = h0 * d.x + h1v * d.y;
#pragma unroll
    for (int off = 1; off < 64; off <<= 1) {
        ps += __shfl_xor(ps, off);
        pd += __shfl_xor(pd, off);
    }
    if (lane == 0) { a2s[node] = ps; a2d[node] = pd; }
}

// ---------------- layer-2 aggregate + bias + relu + fused pooling ----------------
// wave per node; 64 lanes = 4 edge-streams x 16 lanes x 8 features.
__global__ __launch_bounds__(256) void agg2pool(const ushort* __restrict__ h2,
                                                const float* __restrict__ a2s,
                                                const float* __restrict__ a2d,
                                                const int* __restrict__ row_start,
                                                const int* __restrict__ srcs,
                                                const float* __restrict__ ex2,
                                                const float* __restrict__ b2,
                                                const int* __restrict__ batch,
                                                const float* __restrict__ w_attn,
                                                const float* __restrict__ b_attn,
                                                const float* __restrict__ w_mask,
                                                const float* __restrict__ b_mask,
                                                float* pooled, int N) {
    int node = blockIdx.x * 4 + (threadIdx.x >> 6);
    if (node >= N) return;
    int lane = threadIdx.x & 63;
    int eg = lane >> 4, fl = lane & 15;
    int f0 = fl * 8;
    int pbeg = row_start[node], pend = row_start[node + 1];
    float acc[8] = {};
    float den = 0.f;
    for (int p = pbeg + eg; p < pend; p += 4) {
        int s = srcs[p];
        float ex = ex2[p];
        float v[8];
        unpack8(*(const uint4*)(h2 + (size_t)s * 128 + f0), v);
        den += ex;
#pragma unroll
        for (int j = 0; j < 8; ++j) acc[j] += ex * v[j];
    }
    den += __shfl_xor(den, 16);
    den += __shfl_xor(den, 32);
#pragma unroll
    for (int j = 0; j < 8; ++j) {
        acc[j] += __shfl_xor(acc[j], 16);
        acc[j] += __shfl_xor(acc[j], 32);
    }
    // self loop
    {
        float exs = __expf(leaky(a2s[node] + a2d[node]));
        float q[8];
        unpack8(*(const uint4*)(h2 + (size_t)node * 128 + f0), q);
        den += exs;
#pragma unroll
        for (int j = 0; j < 8; ++j) acc[j] += exs * q[j];
    }
    float rden = 1.0f / (den + 1e-16f);
    const float4* bp = (const float4*)(b2 + f0);
    float4 b0 = bp[0], b1v = bp[1];
    float o[8];
    o[0] = fmaxf(acc[0] * rden + b0.x, 0.f);
    o[1] = fmaxf(acc[1] * rden + b0.y, 0.f);
    o[2] = fmaxf(acc[2] * rden + b0.z, 0.f);
    o[3] = fmaxf(acc[3] * rden + b0.w, 0.f);
    o[4] = fmaxf(acc[4] * rden + b1v.x, 0.f);
    o[5] = fmaxf(acc[5] * rden + b1v.y, 0.f);
    o[6] = fmaxf(acc[6] * rden + b1v.z, 0.f);
    o[7] = fmaxf(acc[7] * rden + b1v.w, 0.f);
    // pooling dots: reduce over the 16 lanes of each group (xor strides < 16)
    const float4* wap = (const float4*)(w_attn + f0);
    const float4* wmp = (const float4*)(w_mask + f0);
    float4 wa0 = wap[0], wa1 = wap[1], wm0 = wmp[0], wm1 = wmp[1];
    float pa = o[0]*wa0.x + o[1]*wa0.y + o[2]*wa0.z + o[3]*wa0.w +
               o[4]*wa1.x + o[5]*wa1.y + o[6]*wa1.z + o[7]*wa1.w;
    float pm = o[0]*wm0.x + o[1]*wm0.y + o[2]*wm0.z + o[3]*wm0.w +
               o[4]*wm1.x + o[5]*wm1.y + o[6]*wm1.z + o[7]*wm1.w;
#pragma unroll
    for (int off = 1; off < 16; off <<= 1) {
        pa += __shfl_xor(pa, off);
        pm += __shfl_xor(pm, off);
    }
    float attn = pa + b_attn[0];
    float mask = 1.0f / (1.0f + __expf(-(pm + b_mask[0])));
    float w = attn * mask;
    if (eg == 0) {
        int g = batch[node];
        float* pp = pooled + g * 128 + f0;
#pragma unroll
        for (int j = 0; j < 8; ++j) atomicAdd(pp + j, o[j] * w);
    }
}

// ---------------- final tiny GEMM: out[256,2] ----------------
__global__ void final_kernel(const float* __restrict__ pooled,
                             const float* __restrict__ W_out,
                             const float* __restrict__ b_out,
                             float* __restrict__ out) {
    int tid = blockIdx.x * 256 + threadIdx.x;
    if (tid >= 512) return;
    int g = tid >> 1, o = tid & 1;
    const float* p = pooled + g * 128;
    const float* w = W_out + o * 128;
    float s = 0.f;
#pragma unroll 4
    for (int f = 0; f < 128; ++f) s += p[f] * w[f];
    out[tid] = s + b_out[o];
}

extern "C" void kernel_launch(void* const* d_in, const int* in_sizes, int n_in,
                              void* d_out, int out_size, void* d_ws, size_t ws_size,
                              hipStream_t stream) {
    const float* x        = (const float*)d_in[0];
    const int* edge_index = (const int*)d_in[1];
    const int* batch      = (const int*)d_in[2];
    const float* W1       = (const float*)d_in[3];
    const float* att_src1 = (const float*)d_in[4];
    const float* att_dst1 = (const float*)d_in[5];
    const float* b1       = (const float*)d_in[6];
    const float* W2       = (const float*)d_in[7];
    const float* att_src2 = (const float*)d_in[8];
    const float* att_dst2 = (const float*)d_in[9];
    const float* b2       = (const float*)d_in[10];
    const float* w_attn   = (const float*)d_in[11];
    const float* b_attn   = (const float*)d_in[12];
    const float* w_mask   = (const float*)d_in[13];
    const float* b_mask   = (const float*)d_in[14];
    const float* W_out    = (const float*)d_in[15];
    const float* b_out    = (const float*)d_in[16];
    float* out = (float*)d_out;

    int N = in_sizes[0] / 128;
    int E = in_sizes[1] / 2;
    const int* esrc = edge_index;
    const int* edst = edge_index + E;

    char* ws = (char*)d_ws;
    size_t off = 0;
    auto alloc = [&](size_t bytes) {
        void* p = ws + off;
        off = (off + bytes + 255) & ~(size_t)255;
        return p;
    };
    ushort* xb       = (ushort*)alloc((size_t)N * 128 * 2);    // bf16 x
    ushort* ax       = (ushort*)alloc((size_t)N * 1024 * 2);   // [N,8,128] bf16
    ushort* r1       = (ushort*)alloc((size_t)N * 512 * 2);    // bf16
    ushort* h2       = (ushort*)alloc((size_t)N * 128 * 2);    // bf16
    ushort* w1b      = (ushort*)alloc((size_t)512 * 128 * 2);
    ushort* w2b      = (ushort*)alloc((size_t)128 * 512 * 2);
    float*  v_s      = (float*)alloc((size_t)8 * 128 * 4);
    float*  v_d      = (float*)alloc((size_t)8 * 128 * 4);
    float*  a1s      = (float*)alloc((size_t)N * 8 * 4);
    float*  a1d      = (float*)alloc((size_t)N * 8 * 4);
    float*  a2s      = (float*)alloc((size_t)N * 4);
    float*  a2d      = (float*)alloc((size_t)N * 4);
    int*    row_start= (int*)alloc((size_t)(N + 1) * 4);
    int*    cursor   = (int*)alloc((size_t)N * 4);
    int*    srcs     = (int*)alloc((size_t)E * 4);
    int*    dsts     = (int*)alloc((size_t)E * 4);
    float*  ex1      = (float*)alloc((size_t)E * 8 * 4);
    float*  ex2      = (float*)alloc((size_t)E * 4);
    float*  pooled   = (float*)alloc((size_t)256 * 128 * 4);

    hipMemsetAsync(cursor, 0, (size_t)N * 4, stream);
    hipMemsetAsync(pooled, 0, 256 * 128 * 4, stream);

    dim3 b256(256);
    // converts + score-vector prep
    int nx4 = N * 128 / 4;
    cvt_bf16<<<(nx4 + 255) / 256, b256, 0, stream>>>(x, xb, nx4);
    cvt_bf16<<<(512 * 128 / 4 + 255) / 256, b256, 0, stream>>>(W1, w1b, 512 * 128 / 4);
    cvt_bf16<<<(128 * 512 / 4 + 255) / 256, b256, 0, stream>>>(W2, w2b, 128 * 512 / 4);
    prep_v<<<4, b256, 0, stream>>>(W1, att_src1, att_dst1, v_s, v_d);
    scoresA<<<(N + 3) / 4, b256, 0, stream>>>(xb, v_s, v_d, a1s, a1d, N);
    // CSR build
    count_edges<<<(E + 255) / 256, b256, 0, stream>>>(edst, cursor, E);
    scan_offsets<<<1, 1024, 0, stream>>>(cursor, row_start, cursor, N);
    fill_edges<<<(E + 255) / 256, b256, 0, stream>>>(esrc, edst, cursor, srcs, dsts, E);
    // layer 1
    exp_edges1<<<(E + 255) / 256, b256, 0, stream>>>(srcs, dsts, a1s, a1d, ex1, E);
    agg_x<<<(N + 3) / 4, b256, 0, stream>>>(xb, a1s, a1d, row_start, srcs, ex1, ax, N);
    gemm_grouped<<<dim3((N + 127) / 128, 4), b256, 0, stream>>>(ax, w1b, b1, r1, N);
    // layer 2
    gemm_mfma<<<dim3((N + 127) / 128, 1), b256, 0, stream>>>(r1, w2b, h2, N, 128, 512);
    scores2<<<(N + 3) / 4, b256, 0, stream>>>(h2, att_src2, att_dst2, a2s, a2d, N);
    exp_edges2<<<(E + 255) / 256, b256, 0, stream>>>(srcs, dsts, a2s, a2d, ex2, E);
    agg2pool<<<(N + 3) / 4, b256, 0, stream>>>(h2, a2s, a2d, row_start, srcs, ex2, b2,
                                               batch, w_attn, b_attn, w_mask, b_mask,
                                               pooled, N);
    final_kernel<<<2, b256, 0, stream>>>(pooled, W_out, b_out, out);
}

// Round 7
// 384.975 us; speedup vs baseline: 1.4736x; 1.4736x over previous
//
#include <hip/hip_runtime.h>
#include <math.h>

// R6: fix agg_x register spill (R5: acc[8][8]=64 fp32/lane -> 1 GB scratch traffic,
// 244 us). New agg_x: one wave per (node, head-pair); 4 edge-streams x 16 lanes;
// per lane acc0[8]+acc1[8]+2 den = 18 accumulators -> no spill.
// agg2pool / exp-precompute / commuted GEMM1 unchanged from R5.

#define NEG_SLOPE 0.2f

using bf16x8 = __attribute__((ext_vector_type(8))) __bf16;
using f32x4  = __attribute__((ext_vector_type(4))) float;

// ---------- bf16 helpers ----------
__device__ __forceinline__ ushort f2bf(float f) {
    unsigned u = __float_as_uint(f);
    unsigned r = (u + 0x7FFFu + ((u >> 16) & 1u)) >> 16;   // RNE
    return (ushort)r;
}
__device__ __forceinline__ unsigned pack2(float a, float b) {
    return (unsigned)f2bf(a) | ((unsigned)f2bf(b) << 16);
}
__device__ __forceinline__ void unpack8(uint4 u, float* f) {
    f[0] = __uint_as_float(u.x << 16); f[1] = __uint_as_float(u.x & 0xFFFF0000u);
    f[2] = __uint_as_float(u.y << 16); f[3] = __uint_as_float(u.y & 0xFFFF0000u);
    f[4] = __uint_as_float(u.z << 16); f[5] = __uint_as_float(u.z & 0xFFFF0000u);
    f[6] = __uint_as_float(u.w << 16); f[7] = __uint_as_float(u.w & 0xFFFF0000u);
}

__device__ __forceinline__ float leaky(float e) {
    return e > 0.f ? e : NEG_SLOPE * e;
}

// ---------------- fp32 -> bf16 convert ----------------
__global__ __launch_bounds__(256) void cvt_bf16(const float* __restrict__ in,
                                                ushort* __restrict__ out, int n4) {
    int i = blockIdx.x * 256 + threadIdx.x;
    if (i >= n4) return;
    float4 v = ((const float4*)in)[i];
    uint2 o;
    o.x = pack2(v.x, v.y);
    o.y = pack2(v.z, v.w);
    ((uint2*)out)[i] = o;
}

// ---------------- prep: v_s/v_d[h,f] = sum_c att[h,c] * W1[h*64+c, f] ----------
__global__ __launch_bounds__(256) void prep_v(const float* __restrict__ W1,
                                              const float* __restrict__ att_s,
                                              const float* __restrict__ att_d,
                                              float* __restrict__ v_s,
                                              float* __restrict__ v_d) {
    int tid = blockIdx.x * 256 + threadIdx.x;   // 1024 total
    int h = tid >> 7, f = tid & 127;
    float as = 0.f, ad = 0.f;
    for (int c = 0; c < 64; ++c) {
        float w = W1[(size_t)(h * 64 + c) * 128 + f];
        as += att_s[h * 64 + c] * w;
        ad += att_d[h * 64 + c] * w;
    }
    v_s[tid] = as;
    v_d[tid] = ad;
}

// ---------------- layer-1 scores from x: a1s/a1d [N,8] ----------------
__global__ __launch_bounds__(256) void scoresA(const ushort* __restrict__ xb,
                                               const float* __restrict__ v_s,
                                               const float* __restrict__ v_d,
                                               float* __restrict__ a1s,
                                               float* __restrict__ a1d, int N) {
    int node = blockIdx.x * 4 + (threadIdx.x >> 6);
    if (node >= N) return;
    int lane = threadIdx.x & 63;
    int head = lane >> 3, f0 = (lane & 7) * 16;
    const uint4* xp = (const uint4*)(xb + (size_t)node * 128 + f0);
    float xv[16];
    unpack8(xp[0], xv);
    unpack8(xp[1], xv + 8);
    const float4* sp = (const float4*)(v_s + head * 128 + f0);
    const float4* dp = (const float4*)(v_d + head * 128 + f0);
    float ps = 0.f, pd = 0.f;
#pragma unroll
    for (int q = 0; q < 4; ++q) {
        float4 s4 = sp[q], d4 = dp[q];
        ps += xv[q*4+0]*s4.x + xv[q*4+1]*s4.y + xv[q*4+2]*s4.z + xv[q*4+3]*s4.w;
        pd += xv[q*4+0]*d4.x + xv[q*4+1]*d4.y + xv[q*4+2]*d4.z + xv[q*4+3]*d4.w;
    }
#pragma unroll
    for (int off = 1; off < 8; off <<= 1) {
        ps += __shfl_xor(ps, off);
        pd += __shfl_xor(pd, off);
    }
    if ((lane & 7) == 0) {
        a1s[node * 8 + head] = ps;
        a1d[node * 8 + head] = pd;
    }
}

// ---------------- CSR build ----------------
__global__ void count_edges(const int* __restrict__ dst, int* cnt, int E) {
    int e = blockIdx.x * 256 + threadIdx.x;
    if (e < E) atomicAdd(&cnt[dst[e]], 1);
}

__global__ __launch_bounds__(1024) void scan_offsets(const int* cnt, int* row_start,
                                                     int* cursor, int N) {
    __shared__ int sm[1024];
    int t = threadIdx.x;
    int per = (N + 1023) / 1024;
    int beg = t * per;
    int end = beg + per; if (end > N) end = N;
    int sum = 0;
    for (int i = beg; i < end; ++i) sum += cnt[i];
    sm[t] = sum;
    __syncthreads();
    for (int off = 1; off < 1024; off <<= 1) {
        int add = (t >= off) ? sm[t - off] : 0;
        __syncthreads();
        sm[t] += add;
        __syncthreads();
    }
    int run = sm[t] - sum;
    for (int i = beg; i < end; ++i) {
        int c = cnt[i];
        row_start[i] = run;
        cursor[i] = run;
        run += c;
    }
    if (t == 1023) row_start[N] = run;
}

__global__ void fill_edges(const int* __restrict__ src, const int* __restrict__ dst,
                           int* cursor, int* __restrict__ srcs,
                           int* __restrict__ dsts, int E) {
    int e = blockIdx.x * 256 + threadIdx.x;
    if (e < E) {
        int d = dst[e];
        int pos = atomicAdd(&cursor[d], 1);
        srcs[pos] = src[e];
        dsts[pos] = d;
    }
}

// ---------------- per-edge exp, layer 1: ex1[p,8] ----------------
__global__ __launch_bounds__(256) void exp_edges1(const int* __restrict__ srcs,
                                                  const int* __restrict__ dsts,
                                                  const float* __restrict__ a1s,
                                                  const float* __restrict__ a1d,
                                                  float* __restrict__ ex1, int E) {
    int p = blockIdx.x * 256 + threadIdx.x;
    if (p >= E) return;
    int s = srcs[p], d = dsts[p];
    const float4* sp = (const float4*)(a1s + s * 8);
    const float4* dp = (const float4*)(a1d + d * 8);
    float4 s0 = sp[0], s1 = sp[1], d0 = dp[0], d1 = dp[1];
    float4 o0, o1;
    o0.x = __expf(leaky(s0.x + d0.x));
    o0.y = __expf(leaky(s0.y + d0.y));
    o0.z = __expf(leaky(s0.z + d0.z));
    o0.w = __expf(leaky(s0.w + d0.w));
    o1.x = __expf(leaky(s1.x + d1.x));
    o1.y = __expf(leaky(s1.y + d1.y));
    o1.z = __expf(leaky(s1.z + d1.z));
    o1.w = __expf(leaky(s1.w + d1.w));
    float4* op = (float4*)(ex1 + (size_t)p * 8);
    op[0] = o0; op[1] = o1;
}

// ---------------- per-edge exp, layer 2: ex2[p] ----------------
__global__ __launch_bounds__(256) void exp_edges2(const int* __restrict__ srcs,
                                                  const int* __restrict__ dsts,
                                                  const float* __restrict__ a2s,
                                                  const float* __restrict__ a2d,
                                                  float* __restrict__ ex2, int E) {
    int p = blockIdx.x * 256 + threadIdx.x;
    if (p >= E) return;
    ex2[p] = __expf(leaky(a2s[srcs[p]] + a2d[dsts[p]]));
}

// ---------------- layer-1 aggregate in x-space: ax[N,8,128] bf16 ----------------
// one block per node; wave = head pair hp (heads 2hp, 2hp+1).
// 64 lanes = 4 edge-streams (eg) x 16 lanes (fl), 8 features/lane.
// Per-lane state: acc0[8] + acc1[8] + den0/den1 = 18 fp32 -> no spill.
__global__ __launch_bounds__(256) void agg_x(const ushort* __restrict__ xb,
                                             const float* __restrict__ a1s,
                                             const float* __restrict__ a1d,
                                             const int* __restrict__ row_start,
                                             const int* __restrict__ srcs,
                                             const float* __restrict__ ex1,
                                             ushort* __restrict__ ax, int N) {
    int node = blockIdx.x;
    if (node >= N) return;
    int hp = threadIdx.x >> 6;          // head pair 0..3
    int lane = threadIdx.x & 63;
    int eg = lane >> 4, fl = lane & 15;
    int f0 = fl * 8;
    int pbeg = row_start[node], pend = row_start[node + 1];
    float acc0[8] = {}, acc1[8] = {};
    float den0 = 0.f, den1 = 0.f;
    for (int p = pbeg + eg; p < pend; p += 4) {
        int s = srcs[p];
        float2 e2 = *(const float2*)(ex1 + (size_t)p * 8 + hp * 2);
        float xv[8];
        unpack8(*(const uint4*)(xb + (size_t)s * 128 + f0), xv);
        den0 += e2.x;
        den1 += e2.y;
#pragma unroll
        for (int j = 0; j < 8; ++j) {
            acc0[j] += e2.x * xv[j];
            acc1[j] += e2.y * xv[j];
        }
    }
    // fold 4 edge streams
    den0 += __shfl_xor(den0, 16); den0 += __shfl_xor(den0, 32);
    den1 += __shfl_xor(den1, 16); den1 += __shfl_xor(den1, 32);
#pragma unroll
    for (int j = 0; j < 8; ++j) {
        acc0[j] += __shfl_xor(acc0[j], 16); acc0[j] += __shfl_xor(acc0[j], 32);
        acc1[j] += __shfl_xor(acc1[j], 16); acc1[j] += __shfl_xor(acc1[j], 32);
    }
    // self loop (all lanes hold folded totals)
    {
        float2 sv = *(const float2*)(a1s + node * 8 + hp * 2);
        float2 dv = *(const float2*)(a1d + node * 8 + hp * 2);
        float e0 = __expf(leaky(sv.x + dv.x));
        float e1 = __expf(leaky(sv.y + dv.y));
        float xv[8];
        unpack8(*(const uint4*)(xb + (size_t)node * 128 + f0), xv);
        den0 += e0;
        den1 += e1;
#pragma unroll
        for (int j = 0; j < 8; ++j) {
            acc0[j] += e0 * xv[j];
            acc1[j] += e1 * xv[j];
        }
    }
    // eg 0 writes head 2hp, eg 1 writes head 2hp+1
    if (eg < 2) {
        float den = (eg == 0) ? den0 : den1;
        float rden = 1.0f / (den + 1e-16f);
        float v[8];
#pragma unroll
        for (int j = 0; j < 8; ++j)
            v[j] = ((eg == 0) ? acc0[j] : acc1[j]) * rden;
        uint4 o;
        o.x = pack2(v[0], v[1]);
        o.y = pack2(v[2], v[3]);
        o.z = pack2(v[4], v[5]);
        o.w = pack2(v[6], v[7]);
        *(uint4*)(ax + (size_t)node * 1024 + (2 * hp + eg) * 128 + f0) = o;
    }
}

// ---------------- grouped GEMM: r1[n, h*64+c] = relu(ax[n,h,:]@W1_h^T + b1) ----
#define LDSB 40
__global__ __launch_bounds__(256) void gemm_grouped(const ushort* __restrict__ AX,
                                                    const ushort* __restrict__ W1b,
                                                    const float* __restrict__ b1,
                                                    ushort* __restrict__ r1,
                                                    int M) {
    __shared__ ushort As[2][128 * LDSB];
    __shared__ ushort Bs[128 * LDSB];
    int t = threadIdx.x;
    int wave = t >> 6, lane = t & 63;
    int quad = lane >> 4, l16 = lane & 15;
    int m0 = blockIdx.x * 128;
    int y = blockIdx.y;                 // cols [128y, 128y+128), heads 2y, 2y+1
    int wm = (wave & 1) * 64;
    int wn = (wave >> 1) * 64;
    int hsel = wn >> 6;
    int srow = t >> 1;
    int sseg = (t & 1) * 16;
    f32x4 acc[4][4] = {};
    for (int k0 = 0; k0 < 128; k0 += 32) {
        uint4 a0v0, a0v1, a1v0, a1v1, bv0, bv1;
        {
            int grow = m0 + srow;
            if (grow < M) {
                const uint4* g0 = (const uint4*)(AX + (size_t)grow * 1024 + (2 * y) * 128 + k0 + sseg);
                const uint4* g1 = (const uint4*)(AX + (size_t)grow * 1024 + (2 * y + 1) * 128 + k0 + sseg);
                a0v0 = g0[0]; a0v1 = g0[1];
                a1v0 = g1[0]; a1v1 = g1[1];
            } else {
                a0v0 = make_uint4(0, 0, 0, 0); a0v1 = a0v0; a1v0 = a0v0; a1v1 = a0v0;
            }
            const uint4* gq = (const uint4*)(W1b + (size_t)(y * 128 + srow) * 128 + k0 + sseg);
            bv0 = gq[0]; bv1 = gq[1];
        }
        __syncthreads();
        *(uint4*)&As[0][srow * LDSB + sseg]     = a0v0;
        *(uint4*)&As[0][srow * LDSB + sseg + 8] = a0v1;
        *(uint4*)&As[1][srow * LDSB + sseg]     = a1v0;
        *(uint4*)&As[1][srow * LDSB + sseg + 8] = a1v1;
        *(uint4*)&Bs[srow * LDSB + sseg]        = bv0;
        *(uint4*)&Bs[srow * LDSB + sseg + 8]    = bv1;
        __syncthreads();
        bf16x8 af[4], bf[4];
#pragma unroll
        for (int i = 0; i < 4; ++i)
            af[i] = *(const bf16x8*)&As[hsel][(wm + i * 16 + l16) * LDSB + quad * 8];
#pragma unroll
        for (int j = 0; j < 4; ++j)
            bf[j] = *(const bf16x8*)&Bs[(wn + j * 16 + l16) * LDSB + quad * 8];
#pragma unroll
        for (int i = 0; i < 4; ++i)
#pragma unroll
            for (int j = 0; j < 4; ++j)
                acc[i][j] = __builtin_amdgcn_mfma_f32_16x16x32_bf16(
                    af[i], bf[j], acc[i][j], 0, 0, 0);
    }
#pragma unroll
    for (int i = 0; i < 4; ++i) {
#pragma unroll
        for (int r = 0; r < 4; ++r) {
            int grow = m0 + wm + i * 16 + quad * 4 + r;
            if (grow < M) {
#pragma unroll
                for (int j = 0; j < 4; ++j) {
                    int gcol = y * 128 + wn + j * 16 + l16;
                    float v = fmaxf(acc[i][j][r] + b1[gcol], 0.f);
                    r1[(size_t)grow * 512 + gcol] = f2bf(v);
                }
            }
        }
    }
}

// ---------------- MFMA GEMM (layer 2): C[M,N] = A[M,K]*B[N,K]^T, bf16 ----------
__global__ __launch_bounds__(256) void gemm_mfma(const ushort* __restrict__ A,
                                                 const ushort* __restrict__ B,
                                                 ushort* __restrict__ C,
                                                 int M, int N, int K) {
    __shared__ ushort As[128 * LDSB];
    __shared__ ushort Bs[128 * LDSB];
    int t = threadIdx.x;
    int wave = t >> 6, lane = t & 63;
    int quad = lane >> 4, l16 = lane & 15;
    int m0 = blockIdx.x * 128;
    int n0 = blockIdx.y * 128;
    int wm = (wave & 1) * 64;
    int wn = (wave >> 1) * 64;
    int srow = t >> 1;
    int sseg = (t & 1) * 16;
    f32x4 acc[4][4] = {};
    for (int k0 = 0; k0 < K; k0 += 32) {
        uint4 av0, av1, bv0, bv1;
        {
            int grow = m0 + srow;
            if (grow < M) {
                const uint4* gp = (const uint4*)(A + (size_t)grow * K + k0 + sseg);
                av0 = gp[0]; av1 = gp[1];
            } else {
                av0 = make_uint4(0, 0, 0, 0); av1 = av0;
            }
            const uint4* gq = (const uint4*)(B + (size_t)(n0 + srow) * K + k0 + sseg);
            bv0 = gq[0]; bv1 = gq[1];
        }
        __syncthreads();
        *(uint4*)&As[srow * LDSB + sseg]     = av0;
        *(uint4*)&As[srow * LDSB + sseg + 8] = av1;
        *(uint4*)&Bs[srow * LDSB + sseg]     = bv0;
        *(uint4*)&Bs[srow * LDSB + sseg + 8] = bv1;
        __syncthreads();
        bf16x8 af[4], bf[4];
#pragma unroll
        for (int i = 0; i < 4; ++i)
            af[i] = *(const bf16x8*)&As[(wm + i * 16 + l16) * LDSB + quad * 8];
#pragma unroll
        for (int j = 0; j < 4; ++j)
            bf[j] = *(const bf16x8*)&Bs[(wn + j * 16 + l16) * LDSB + quad * 8];
#pragma unroll
        for (int i = 0; i < 4; ++i)
#pragma unroll
            for (int j = 0; j < 4; ++j)
                acc[i][j] = __builtin_amdgcn_mfma_f32_16x16x32_bf16(
                    af[i], bf[j], acc[i][j], 0, 0, 0);
    }
#pragma unroll
    for (int i = 0; i < 4; ++i) {
#pragma unroll
        for (int r = 0; r < 4; ++r) {
            int grow = m0 + wm + i * 16 + quad * 4 + r;
            if (grow < M) {
#pragma unroll
                for (int j = 0; j < 4; ++j) {
                    int gcol = n0 + wn + j * 16 + l16;
                    C[(size_t)grow * N + gcol] = f2bf(acc[i][j][r]);
                }
            }
        }
    }
}

// ---------------- layer-2 scores ----------------
__global__ __launch_bounds__(256) void scores2(const ushort* __restrict__ h2,
                                               const float* __restrict__ att_s,
                                               const float* __restrict__ att_d,
                                               float* __restrict__ a2s,
                                               float* __restrict__ a2d, int N) {
    int node = blockIdx.x * 4 + (threadIdx.x >> 6);
    if (node >= N) return;
    int lane = threadIdx.x & 63;
    unsigned u = *(const unsigned*)(h2 + (size_t)node * 128 + lane * 2);
    float h0 = __uint_as_float(u << 16), h1v = __uint_as_float(u & 0xFFFF0000u);
    float2 s = *(const float2*)(att_s + lane * 2);
    float2 d = *(const float2*)(att_d + lane * 2);
    float ps = h0 * s.x + h1v * s.y;
    float pd = h0 * d.x + h1v * d.y;
#pragma unroll
    for (int off = 1; off < 64; off <<= 1) {
        ps += __shfl_xor(ps, off);
        pd += __shfl_xor(pd, off);
    }
    if (lane == 0) { a2s[node] = ps; a2d[node] = pd; }
}

// ---------------- layer-2 aggregate + bias + relu + fused pooling ----------------
// wave per node; 64 lanes = 4 edge-streams x 16 lanes x 8 features.
__global__ __launch_bounds__(256) void agg2pool(const ushort* __restrict__ h2,
                                                const float* __restrict__ a2s,
                                                const float* __restrict__ a2d,
                                                const int* __restrict__ row_start,
                                                const int* __restrict__ srcs,
                                                const float* __restrict__ ex2,
                                                const float* __restrict__ b2,
                                                const int* __restrict__ batch,
                                                const float* __restrict__ w_attn,
                                                const float* __restrict__ b_attn,
                                                const float* __restrict__ w_mask,
                                                const float* __restrict__ b_mask,
                                                float* pooled, int N) {
    int node = blockIdx.x * 4 + (threadIdx.x >> 6);
    if (node >= N) return;
    int lane = threadIdx.x & 63;
    int eg = lane >> 4, fl = lane & 15;
    int f0 = fl * 8;
    int pbeg = row_start[node], pend = row_start[node + 1];
    float acc[8] = {};
    float den = 0.f;
    for (int p = pbeg + eg; p < pend; p += 4) {
        int s = srcs[p];
        float ex = ex2[p];
        float v[8];
        unpack8(*(const uint4*)(h2 + (size_t)s * 128 + f0), v);
        den += ex;
#pragma unroll
        for (int j = 0; j < 8; ++j) acc[j] += ex * v[j];
    }
    den += __shfl_xor(den, 16);
    den += __shfl_xor(den, 32);
#pragma unroll
    for (int j = 0; j < 8; ++j) {
        acc[j] += __shfl_xor(acc[j], 16);
        acc[j] += __shfl_xor(acc[j], 32);
    }
    // self loop
    {
        float exs = __expf(leaky(a2s[node] + a2d[node]));
        float q[8];
        unpack8(*(const uint4*)(h2 + (size_t)node * 128 + f0), q);
        den += exs;
#pragma unroll
        for (int j = 0; j < 8; ++j) acc[j] += exs * q[j];
    }
    float rden = 1.0f / (den + 1e-16f);
    const float4* bp = (const float4*)(b2 + f0);
    float4 b0 = bp[0], b1v = bp[1];
    float o[8];
    o[0] = fmaxf(acc[0] * rden + b0.x, 0.f);
    o[1] = fmaxf(acc[1] * rden + b0.y, 0.f);
    o[2] = fmaxf(acc[2] * rden + b0.z, 0.f);
    o[3] = fmaxf(acc[3] * rden + b0.w, 0.f);
    o[4] = fmaxf(acc[4] * rden + b1v.x, 0.f);
    o[5] = fmaxf(acc[5] * rden + b1v.y, 0.f);
    o[6] = fmaxf(acc[6] * rden + b1v.z, 0.f);
    o[7] = fmaxf(acc[7] * rden + b1v.w, 0.f);
    // pooling dots: reduce over the 16 lanes of each group (xor strides < 16)
    const float4* wap = (const float4*)(w_attn + f0);
    const float4* wmp = (const float4*)(w_mask + f0);
    float4 wa0 = wap[0], wa1 = wap[1], wm0 = wmp[0], wm1 = wmp[1];
    float pa = o[0]*wa0.x + o[1]*wa0.y + o[2]*wa0.z + o[3]*wa0.w +
               o[4]*wa1.x + o[5]*wa1.y + o[6]*wa1.z + o[7]*wa1.w;
    float pm = o[0]*wm0.x + o[1]*wm0.y + o[2]*wm0.z + o[3]*wm0.w +
               o[4]*wm1.x + o[5]*wm1.y + o[6]*wm1.z + o[7]*wm1.w;
#pragma unroll
    for (int off = 1; off < 16; off <<= 1) {
        pa += __shfl_xor(pa, off);
        pm += __shfl_xor(pm, off);
    }
    float attn = pa + b_attn[0];
    float mask = 1.0f / (1.0f + __expf(-(pm + b_mask[0])));
    float w = attn * mask;
    if (eg == 0) {
        int g = batch[node];
        float* pp = pooled + g * 128 + f0;
#pragma unroll
        for (int j = 0; j < 8; ++j) atomicAdd(pp + j, o[j] * w);
    }
}

// ---------------- final tiny GEMM: out[256,2] ----------------
__global__ void final_kernel(const float* __restrict__ pooled,
                             const float* __restrict__ W_out,
                             const float* __restrict__ b_out,
                             float* __restrict__ out) {
    int tid = blockIdx.x * 256 + threadIdx.x;
    if (tid >= 512) return;
    int g = tid >> 1, o = tid & 1;
    const float* p = pooled + g * 128;
    const float* w = W_out + o * 128;
    float s = 0.f;
#pragma unroll 4
    for (int f = 0; f < 128; ++f) s += p[f] * w[f];
    out[tid] = s + b_out[o];
}

extern "C" void kernel_launch(void* const* d_in, const int* in_sizes, int n_in,
                              void* d_out, int out_size, void* d_ws, size_t ws_size,
                              hipStream_t stream) {
    const float* x        = (const float*)d_in[0];
    const int* edge_index = (const int*)d_in[1];
    const int* batch      = (const int*)d_in[2];
    const float* W1       = (const float*)d_in[3];
    const float* att_src1 = (const float*)d_in[4];
    const float* att_dst1 = (const float*)d_in[5];
    const float* b1       = (const float*)d_in[6];
    const float* W2       = (const float*)d_in[7];
    const float* att_src2 = (const float*)d_in[8];
    const float* att_dst2 = (const float*)d_in[9];
    const float* b2       = (const float*)d_in[10];
    const float* w_attn   = (const float*)d_in[11];
    const float* b_attn   = (const float*)d_in[12];
    const float* w_mask   = (const float*)d_in[13];
    const float* b_mask   = (const float*)d_in[14];
    const float* W_out    = (const float*)d_in[15];
    const float* b_out    = (const float*)d_in[16];
    float* out = (float*)d_out;

    int N = in_sizes[0] / 128;
    int E = in_sizes[1] / 2;
    const int* esrc = edge_index;
    const int* edst = edge_index + E;

    char* ws = (char*)d_ws;
    size_t off = 0;
    auto alloc = [&](size_t bytes) {
        void* p = ws + off;
        off = (off + bytes + 255) & ~(size_t)255;
        return p;
    };
    ushort* xb       = (ushort*)alloc((size_t)N * 128 * 2);    // bf16 x
    ushort* ax       = (ushort*)alloc((size_t)N * 1024 * 2);   // [N,8,128] bf16
    ushort* r1       = (ushort*)alloc((size_t)N * 512 * 2);    // bf16
    ushort* h2       = (ushort*)alloc((size_t)N * 128 * 2);    // bf16
    ushort* w1b      = (ushort*)alloc((size_t)512 * 128 * 2);
    ushort* w2b      = (ushort*)alloc((size_t)128 * 512 * 2);
    float*  v_s      = (float*)alloc((size_t)8 * 128 * 4);
    float*  v_d      = (float*)alloc((size_t)8 * 128 * 4);
    float*  a1s      = (float*)alloc((size_t)N * 8 * 4);
    float*  a1d      = (float*)alloc((size_t)N * 8 * 4);
    float*  a2s      = (float*)alloc((size_t)N * 4);
    float*  a2d      = (float*)alloc((size_t)N * 4);
    int*    row_start= (int*)alloc((size_t)(N + 1) * 4);
    int*    cursor   = (int*)alloc((size_t)N * 4);
    int*    srcs     = (int*)alloc((size_t)E * 4);
    int*    dsts     = (int*)alloc((size_t)E * 4);
    float*  ex1      = (float*)alloc((size_t)E * 8 * 4);
    float*  ex2      = (float*)alloc((size_t)E * 4);
    float*  pooled   = (float*)alloc((size_t)256 * 128 * 4);

    hipMemsetAsync(cursor, 0, (size_t)N * 4, stream);
    hipMemsetAsync(pooled, 0, 256 * 128 * 4, stream);

    dim3 b256(256);
    // converts + score-vector prep
    int nx4 = N * 128 / 4;
    cvt_bf16<<<(nx4 + 255) / 256, b256, 0, stream>>>(x, xb, nx4);
    cvt_bf16<<<(512 * 128 / 4 + 255) / 256, b256, 0, stream>>>(W1, w1b, 512 * 128 / 4);
    cvt_bf16<<<(128 * 512 / 4 + 255) / 256, b256, 0, stream>>>(W2, w2b, 128 * 512 / 4);
    prep_v<<<4, b256, 0, stream>>>(W1, att_src1, att_dst1, v_s, v_d);
    scoresA<<<(N + 3) / 4, b256, 0, stream>>>(xb, v_s, v_d, a1s, a1d, N);
    // CSR build
    count_edges<<<(E + 255) / 256, b256, 0, stream>>>(edst, cursor, E);
    scan_offsets<<<1, 1024, 0, stream>>>(cursor, row_start, cursor, N);
    fill_edges<<<(E + 255) / 256, b256, 0, stream>>>(esrc, edst, cursor, srcs, dsts, E);
    // layer 1
    exp_edges1<<<(E + 255) / 256, b256, 0, stream>>>(srcs, dsts, a1s, a1d, ex1, E);
    agg_x<<<N, b256, 0, stream>>>(xb, a1s, a1d, row_start, srcs, ex1, ax, N);
    gemm_grouped<<<dim3((N + 127) / 128, 4), b256, 0, stream>>>(ax, w1b, b1, r1, N);
    // layer 2
    gemm_mfma<<<dim3((N + 127) / 128, 1), b256, 0, stream>>>(r1, w2b, h2, N, 128, 512);
    scores2<<<(N + 3) / 4, b256, 0, stream>>>(h2, att_src2, att_dst2, a2s, a2d, N);
    exp_edges2<<<(E + 255) / 256, b256, 0, stream>>>(srcs, dsts, a2s, a2d, ex2, E);
    agg2pool<<<(N + 3) / 4, b256, 0, stream>>>(h2, a2s, a2d, row_start, srcs, ex2, b2,
                                               batch, w_attn, b_attn, w_mask, b_mask,
                                               pooled, N);
    final_kernel<<<2, b256, 0, stream>>>(pooled, W_out, b_out, out);
}

// Round 8
// 336.260 us; speedup vs baseline: 1.6871x; 1.1449x over previous
//
#include <hip/hip_runtime.h>
#include <math.h>

// R7: kill the pooling atomics (R6: 2.56M device-scope fp32 atomicAdds onto a
// 128 KB buffer = 80 MB fabric RMW traffic, ~1250 serialized RMWs/line -> 99 us
// with 8% VALUBusy). batch is SORTED, so pooling is a contiguous segment-sum:
//   agg2 writes wh[n] = w * relu(aggregate) coalesced (no atomics);
//   pool_seg: 1 block/graph, binary-search range, column-sum, fused final GEMM.
// pooled buffer, its memset, and final_kernel deleted.

#define NEG_SLOPE 0.2f

using bf16x8 = __attribute__((ext_vector_type(8))) __bf16;
using f32x4  = __attribute__((ext_vector_type(4))) float;

// ---------- bf16 helpers ----------
__device__ __forceinline__ ushort f2bf(float f) {
    unsigned u = __float_as_uint(f);
    unsigned r = (u + 0x7FFFu + ((u >> 16) & 1u)) >> 16;   // RNE
    return (ushort)r;
}
__device__ __forceinline__ unsigned pack2(float a, float b) {
    return (unsigned)f2bf(a) | ((unsigned)f2bf(b) << 16);
}
__device__ __forceinline__ void unpack8(uint4 u, float* f) {
    f[0] = __uint_as_float(u.x << 16); f[1] = __uint_as_float(u.x & 0xFFFF0000u);
    f[2] = __uint_as_float(u.y << 16); f[3] = __uint_as_float(u.y & 0xFFFF0000u);
    f[4] = __uint_as_float(u.z << 16); f[5] = __uint_as_float(u.z & 0xFFFF0000u);
    f[6] = __uint_as_float(u.w << 16); f[7] = __uint_as_float(u.w & 0xFFFF0000u);
}

__device__ __forceinline__ float leaky(float e) {
    return e > 0.f ? e : NEG_SLOPE * e;
}

// ---------------- fp32 -> bf16 convert ----------------
__global__ __launch_bounds__(256) void cvt_bf16(const float* __restrict__ in,
                                                ushort* __restrict__ out, int n4) {
    int i = blockIdx.x * 256 + threadIdx.x;
    if (i >= n4) return;
    float4 v = ((const float4*)in)[i];
    uint2 o;
    o.x = pack2(v.x, v.y);
    o.y = pack2(v.z, v.w);
    ((uint2*)out)[i] = o;
}

// ---------------- prep: v_s/v_d[h,f] = sum_c att[h,c] * W1[h*64+c, f] ----------
__global__ __launch_bounds__(256) void prep_v(const float* __restrict__ W1,
                                              const float* __restrict__ att_s,
                                              const float* __restrict__ att_d,
                                              float* __restrict__ v_s,
                                              float* __restrict__ v_d) {
    int tid = blockIdx.x * 256 + threadIdx.x;   // 1024 total
    int h = tid >> 7, f = tid & 127;
    float as = 0.f, ad = 0.f;
    for (int c = 0; c < 64; ++c) {
        float w = W1[(size_t)(h * 64 + c) * 128 + f];
        as += att_s[h * 64 + c] * w;
        ad += att_d[h * 64 + c] * w;
    }
    v_s[tid] = as;
    v_d[tid] = ad;
}

// ---------------- layer-1 scores from x: a1s/a1d [N,8] ----------------
__global__ __launch_bounds__(256) void scoresA(const ushort* __restrict__ xb,
                                               const float* __restrict__ v_s,
                                               const float* __restrict__ v_d,
                                               float* __restrict__ a1s,
                                               float* __restrict__ a1d, int N) {
    int node = blockIdx.x * 4 + (threadIdx.x >> 6);
    if (node >= N) return;
    int lane = threadIdx.x & 63;
    int head = lane >> 3, f0 = (lane & 7) * 16;
    const uint4* xp = (const uint4*)(xb + (size_t)node * 128 + f0);
    float xv[16];
    unpack8(xp[0], xv);
    unpack8(xp[1], xv + 8);
    const float4* sp = (const float4*)(v_s + head * 128 + f0);
    const float4* dp = (const float4*)(v_d + head * 128 + f0);
    float ps = 0.f, pd = 0.f;
#pragma unroll
    for (int q = 0; q < 4; ++q) {
        float4 s4 = sp[q], d4 = dp[q];
        ps += xv[q*4+0]*s4.x + xv[q*4+1]*s4.y + xv[q*4+2]*s4.z + xv[q*4+3]*s4.w;
        pd += xv[q*4+0]*d4.x + xv[q*4+1]*d4.y + xv[q*4+2]*d4.z + xv[q*4+3]*d4.w;
    }
#pragma unroll
    for (int off = 1; off < 8; off <<= 1) {
        ps += __shfl_xor(ps, off);
        pd += __shfl_xor(pd, off);
    }
    if ((lane & 7) == 0) {
        a1s[node * 8 + head] = ps;
        a1d[node * 8 + head] = pd;
    }
}

// ---------------- CSR build ----------------
__global__ void count_edges(const int* __restrict__ dst, int* cnt, int E) {
    int e = blockIdx.x * 256 + threadIdx.x;
    if (e < E) atomicAdd(&cnt[dst[e]], 1);
}

__global__ __launch_bounds__(1024) void scan_offsets(const int* cnt, int* row_start,
                                                     int* cursor, int N) {
    __shared__ int sm[1024];
    int t = threadIdx.x;
    int per = (N + 1023) / 1024;
    int beg = t * per;
    int end = beg + per; if (end > N) end = N;
    int sum = 0;
    for (int i = beg; i < end; ++i) sum += cnt[i];
    sm[t] = sum;
    __syncthreads();
    for (int off = 1; off < 1024; off <<= 1) {
        int add = (t >= off) ? sm[t - off] : 0;
        __syncthreads();
        sm[t] += add;
        __syncthreads();
    }
    int run = sm[t] - sum;
    for (int i = beg; i < end; ++i) {
        int c = cnt[i];
        row_start[i] = run;
        cursor[i] = run;
        run += c;
    }
    if (t == 1023) row_start[N] = run;
}

__global__ void fill_edges(const int* __restrict__ src, const int* __restrict__ dst,
                           int* cursor, int* __restrict__ srcs,
                           int* __restrict__ dsts, int E) {
    int e = blockIdx.x * 256 + threadIdx.x;
    if (e < E) {
        int d = dst[e];
        int pos = atomicAdd(&cursor[d], 1);
        srcs[pos] = src[e];
        dsts[pos] = d;
    }
}

// ---------------- per-edge exp, layer 1: ex1[p,8] ----------------
__global__ __launch_bounds__(256) void exp_edges1(const int* __restrict__ srcs,
                                                  const int* __restrict__ dsts,
                                                  const float* __restrict__ a1s,
                                                  const float* __restrict__ a1d,
                                                  float* __restrict__ ex1, int E) {
    int p = blockIdx.x * 256 + threadIdx.x;
    if (p >= E) return;
    int s = srcs[p], d = dsts[p];
    const float4* sp = (const float4*)(a1s + s * 8);
    const float4* dp = (const float4*)(a1d + d * 8);
    float4 s0 = sp[0], s1 = sp[1], d0 = dp[0], d1 = dp[1];
    float4 o0, o1;
    o0.x = __expf(leaky(s0.x + d0.x));
    o0.y = __expf(leaky(s0.y + d0.y));
    o0.z = __expf(leaky(s0.z + d0.z));
    o0.w = __expf(leaky(s0.w + d0.w));
    o1.x = __expf(leaky(s1.x + d1.x));
    o1.y = __expf(leaky(s1.y + d1.y));
    o1.z = __expf(leaky(s1.z + d1.z));
    o1.w = __expf(leaky(s1.w + d1.w));
    float4* op = (float4*)(ex1 + (size_t)p * 8);
    op[0] = o0; op[1] = o1;
}

// ---------------- per-edge exp, layer 2: ex2[p] ----------------
__global__ __launch_bounds__(256) void exp_edges2(const int* __restrict__ srcs,
                                                  const int* __restrict__ dsts,
                                                  const float* __restrict__ a2s,
                                                  const float* __restrict__ a2d,
                                                  float* __restrict__ ex2, int E) {
    int p = blockIdx.x * 256 + threadIdx.x;
    if (p >= E) return;
    ex2[p] = __expf(leaky(a2s[srcs[p]] + a2d[dsts[p]]));
}

// ---------------- layer-1 aggregate in x-space: ax[N,8,128] bf16 ----------------
// one block per node; wave = head pair hp (heads 2hp, 2hp+1).
// 64 lanes = 4 edge-streams (eg) x 16 lanes (fl), 8 features/lane.
__global__ __launch_bounds__(256) void agg_x(const ushort* __restrict__ xb,
                                             const float* __restrict__ a1s,
                                             const float* __restrict__ a1d,
                                             const int* __restrict__ row_start,
                                             const int* __restrict__ srcs,
                                             const float* __restrict__ ex1,
                                             ushort* __restrict__ ax, int N) {
    int node = blockIdx.x;
    if (node >= N) return;
    int hp = threadIdx.x >> 6;          // head pair 0..3
    int lane = threadIdx.x & 63;
    int eg = lane >> 4, fl = lane & 15;
    int f0 = fl * 8;
    int pbeg = row_start[node], pend = row_start[node + 1];
    float acc0[8] = {}, acc1[8] = {};
    float den0 = 0.f, den1 = 0.f;
    for (int p = pbeg + eg; p < pend; p += 4) {
        int s = srcs[p];
        float2 e2 = *(const float2*)(ex1 + (size_t)p * 8 + hp * 2);
        float xv[8];
        unpack8(*(const uint4*)(xb + (size_t)s * 128 + f0), xv);
        den0 += e2.x;
        den1 += e2.y;
#pragma unroll
        for (int j = 0; j < 8; ++j) {
            acc0[j] += e2.x * xv[j];
            acc1[j] += e2.y * xv[j];
        }
    }
    // fold 4 edge streams
    den0 += __shfl_xor(den0, 16); den0 += __shfl_xor(den0, 32);
    den1 += __shfl_xor(den1, 16); den1 += __shfl_xor(den1, 32);
#pragma unroll
    for (int j = 0; j < 8; ++j) {
        acc0[j] += __shfl_xor(acc0[j], 16); acc0[j] += __shfl_xor(acc0[j], 32);
        acc1[j] += __shfl_xor(acc1[j], 16); acc1[j] += __shfl_xor(acc1[j], 32);
    }
    // self loop (all lanes hold folded totals)
    {
        float2 sv = *(const float2*)(a1s + node * 8 + hp * 2);
        float2 dv = *(const float2*)(a1d + node * 8 + hp * 2);
        float e0 = __expf(leaky(sv.x + dv.x));
        float e1 = __expf(leaky(sv.y + dv.y));
        float xv[8];
        unpack8(*(const uint4*)(xb + (size_t)node * 128 + f0), xv);
        den0 += e0;
        den1 += e1;
#pragma unroll
        for (int j = 0; j < 8; ++j) {
            acc0[j] += e0 * xv[j];
            acc1[j] += e1 * xv[j];
        }
    }
    // eg 0 writes head 2hp, eg 1 writes head 2hp+1
    if (eg < 2) {
        float den = (eg == 0) ? den0 : den1;
        float rden = 1.0f / (den + 1e-16f);
        float v[8];
#pragma unroll
        for (int j = 0; j < 8; ++j)
            v[j] = ((eg == 0) ? acc0[j] : acc1[j]) * rden;
        uint4 o;
        o.x = pack2(v[0], v[1]);
        o.y = pack2(v[2], v[3]);
        o.z = pack2(v[4], v[5]);
        o.w = pack2(v[6], v[7]);
        *(uint4*)(ax + (size_t)node * 1024 + (2 * hp + eg) * 128 + f0) = o;
    }
}

// ---------------- grouped GEMM: r1[n, h*64+c] = relu(ax[n,h,:]@W1_h^T + b1) ----
#define LDSB 40
__global__ __launch_bounds__(256) void gemm_grouped(const ushort* __restrict__ AX,
                                                    const ushort* __restrict__ W1b,
                                                    const float* __restrict__ b1,
                                                    ushort* __restrict__ r1,
                                                    int M) {
    __shared__ ushort As[2][128 * LDSB];
    __shared__ ushort Bs[128 * LDSB];
    int t = threadIdx.x;
    int wave = t >> 6, lane = t & 63;
    int quad = lane >> 4, l16 = lane & 15;
    int m0 = blockIdx.x * 128;
    int y = blockIdx.y;                 // cols [128y, 128y+128), heads 2y, 2y+1
    int wm = (wave & 1) * 64;
    int wn = (wave >> 1) * 64;
    int hsel = wn >> 6;
    int srow = t >> 1;
    int sseg = (t & 1) * 16;
    f32x4 acc[4][4] = {};
    for (int k0 = 0; k0 < 128; k0 += 32) {
        uint4 a0v0, a0v1, a1v0, a1v1, bv0, bv1;
        {
            int grow = m0 + srow;
            if (grow < M) {
                const uint4* g0 = (const uint4*)(AX + (size_t)grow * 1024 + (2 * y) * 128 + k0 + sseg);
                const uint4* g1 = (const uint4*)(AX + (size_t)grow * 1024 + (2 * y + 1) * 128 + k0 + sseg);
                a0v0 = g0[0]; a0v1 = g0[1];
                a1v0 = g1[0]; a1v1 = g1[1];
            } else {
                a0v0 = make_uint4(0, 0, 0, 0); a0v1 = a0v0; a1v0 = a0v0; a1v1 = a0v0;
            }
            const uint4* gq = (const uint4*)(W1b + (size_t)(y * 128 + srow) * 128 + k0 + sseg);
            bv0 = gq[0]; bv1 = gq[1];
        }
        __syncthreads();
        *(uint4*)&As[0][srow * LDSB + sseg]     = a0v0;
        *(uint4*)&As[0][srow * LDSB + sseg + 8] = a0v1;
        *(uint4*)&As[1][srow * LDSB + sseg]     = a1v0;
        *(uint4*)&As[1][srow * LDSB + sseg + 8] = a1v1;
        *(uint4*)&Bs[srow * LDSB + sseg]        = bv0;
        *(uint4*)&Bs[srow * LDSB + sseg + 8]    = bv1;
        __syncthreads();
        bf16x8 af[4], bf[4];
#pragma unroll
        for (int i = 0; i < 4; ++i)
            af[i] = *(const bf16x8*)&As[hsel][(wm + i * 16 + l16) * LDSB + quad * 8];
#pragma unroll
        for (int j = 0; j < 4; ++j)
            bf[j] = *(const bf16x8*)&Bs[(wn + j * 16 + l16) * LDSB + quad * 8];
#pragma unroll
        for (int i = 0; i < 4; ++i)
#pragma unroll
            for (int j = 0; j < 4; ++j)
                acc[i][j] = __builtin_amdgcn_mfma_f32_16x16x32_bf16(
                    af[i], bf[j], acc[i][j], 0, 0, 0);
    }
#pragma unroll
    for (int i = 0; i < 4; ++i) {
#pragma unroll
        for (int r = 0; r < 4; ++r) {
            int grow = m0 + wm + i * 16 + quad * 4 + r;
            if (grow < M) {
#pragma unroll
                for (int j = 0; j < 4; ++j) {
                    int gcol = y * 128 + wn + j * 16 + l16;
                    float v = fmaxf(acc[i][j][r] + b1[gcol], 0.f);
                    r1[(size_t)grow * 512 + gcol] = f2bf(v);
                }
            }
        }
    }
}

// ---------------- MFMA GEMM (layer 2): C[M,N] = A[M,K]*B[N,K]^T, bf16 ----------
__global__ __launch_bounds__(256) void gemm_mfma(const ushort* __restrict__ A,
                                                 const ushort* __restrict__ B,
                                                 ushort* __restrict__ C,
                                                 int M, int N, int K) {
    __shared__ ushort As[128 * LDSB];
    __shared__ ushort Bs[128 * LDSB];
    int t = threadIdx.x;
    int wave = t >> 6, lane = t & 63;
    int quad = lane >> 4, l16 = lane & 15;
    int m0 = blockIdx.x * 128;
    int n0 = blockIdx.y * 128;
    int wm = (wave & 1) * 64;
    int wn = (wave >> 1) * 64;
    int srow = t >> 1;
    int sseg = (t & 1) * 16;
    f32x4 acc[4][4] = {};
    for (int k0 = 0; k0 < K; k0 += 32) {
        uint4 av0, av1, bv0, bv1;
        {
            int grow = m0 + srow;
            if (grow < M) {
                const uint4* gp = (const uint4*)(A + (size_t)grow * K + k0 + sseg);
                av0 = gp[0]; av1 = gp[1];
            } else {
                av0 = make_uint4(0, 0, 0, 0); av1 = av0;
            }
            const uint4* gq = (const uint4*)(B + (size_t)(n0 + srow) * K + k0 + sseg);
            bv0 = gq[0]; bv1 = gq[1];
        }
        __syncthreads();
        *(uint4*)&As[srow * LDSB + sseg]     = av0;
        *(uint4*)&As[srow * LDSB + sseg + 8] = av1;
        *(uint4*)&Bs[srow * LDSB + sseg]     = bv0;
        *(uint4*)&Bs[srow * LDSB + sseg + 8] = bv1;
        __syncthreads();
        bf16x8 af[4], bf[4];
#pragma unroll
        for (int i = 0; i < 4; ++i)
            af[i] = *(const bf16x8*)&As[(wm + i * 16 + l16) * LDSB + quad * 8];
#pragma unroll
        for (int j = 0; j < 4; ++j)
            bf[j] = *(const bf16x8*)&Bs[(wn + j * 16 + l16) * LDSB + quad * 8];
#pragma unroll
        for (int i = 0; i < 4; ++i)
#pragma unroll
            for (int j = 0; j < 4; ++j)
                acc[i][j] = __builtin_amdgcn_mfma_f32_16x16x32_bf16(
                    af[i], bf[j], acc[i][j], 0, 0, 0);
    }
#pragma unroll
    for (int i = 0; i < 4; ++i) {
#pragma unroll
        for (int r = 0; r < 4; ++r) {
            int grow = m0 + wm + i * 16 + quad * 4 + r;
            if (grow < M) {
#pragma unroll
                for (int j = 0; j < 4; ++j) {
                    int gcol = n0 + wn + j * 16 + l16;
                    C[(size_t)grow * N + gcol] = f2bf(acc[i][j][r]);
                }
            }
        }
    }
}

// ---------------- layer-2 scores ----------------
__global__ __launch_bounds__(256) void scores2(const ushort* __restrict__ h2,
                                               const float* __restrict__ att_s,
                                               const float* __restrict__ att_d,
                                               float* __restrict__ a2s,
                                               float* __restrict__ a2d, int N) {
    int node = blockIdx.x * 4 + (threadIdx.x >> 6);
    if (node >= N) return;
    int lane = threadIdx.x & 63;
    unsigned u = *(const unsigned*)(h2 + (size_t)node * 128 + lane * 2);
    float h0 = __uint_as_float(u << 16), h1v = __uint_as_float(u & 0xFFFF0000u);
    float2 s = *(const float2*)(att_s + lane * 2);
    float2 d = *(const float2*)(att_d + lane * 2);
    float ps = h0 * s.x + h1v * s.y;
    float pd = h0 * d.x + h1v * d.y;
#pragma unroll
    for (int off = 1; off < 64; off <<= 1) {
        ps += __shfl_xor(ps, off);
        pd += __shfl_xor(pd, off);
    }
    if (lane == 0) { a2s[node] = ps; a2d[node] = pd; }
}

// ---------------- layer-2 aggregate + bias + relu + attention weight ----------
// wave per node; 64 lanes = 4 edge-streams x 16 lanes x 8 features.
// Writes wh[n] = w * relu(agg + b2) coalesced -- NO atomics.
__global__ __launch_bounds__(256) void agg2(const ushort* __restrict__ h2,
                                            const float* __restrict__ a2s,
                                            const float* __restrict__ a2d,
                                            const int* __restrict__ row_start,
                                            const int* __restrict__ srcs,
                                            const float* __restrict__ ex2,
                                            const float* __restrict__ b2,
                                            const float* __restrict__ w_attn,
                                            const float* __restrict__ b_attn,
                                            const float* __restrict__ w_mask,
                                            const float* __restrict__ b_mask,
                                            float* __restrict__ wh, int N) {
    int node = blockIdx.x * 4 + (threadIdx.x >> 6);
    if (node >= N) return;
    int lane = threadIdx.x & 63;
    int eg = lane >> 4, fl = lane & 15;
    int f0 = fl * 8;
    int pbeg = row_start[node], pend = row_start[node + 1];
    float acc[8] = {};
    float den = 0.f;
    for (int p = pbeg + eg; p < pend; p += 4) {
        int s = srcs[p];
        float ex = ex2[p];
        float v[8];
        unpack8(*(const uint4*)(h2 + (size_t)s * 128 + f0), v);
        den += ex;
#pragma unroll
        for (int j = 0; j < 8; ++j) acc[j] += ex * v[j];
    }
    den += __shfl_xor(den, 16);
    den += __shfl_xor(den, 32);
#pragma unroll
    for (int j = 0; j < 8; ++j) {
        acc[j] += __shfl_xor(acc[j], 16);
        acc[j] += __shfl_xor(acc[j], 32);
    }
    // self loop
    {
        float exs = __expf(leaky(a2s[node] + a2d[node]));
        float q[8];
        unpack8(*(const uint4*)(h2 + (size_t)node * 128 + f0), q);
        den += exs;
#pragma unroll
        for (int j = 0; j < 8; ++j) acc[j] += exs * q[j];
    }
    float rden = 1.0f / (den + 1e-16f);
    const float4* bp = (const float4*)(b2 + f0);
    float4 b0 = bp[0], b1v = bp[1];
    float o[8];
    o[0] = fmaxf(acc[0] * rden + b0.x, 0.f);
    o[1] = fmaxf(acc[1] * rden + b0.y, 0.f);
    o[2] = fmaxf(acc[2] * rden + b0.z, 0.f);
    o[3] = fmaxf(acc[3] * rden + b0.w, 0.f);
    o[4] = fmaxf(acc[4] * rden + b1v.x, 0.f);
    o[5] = fmaxf(acc[5] * rden + b1v.y, 0.f);
    o[6] = fmaxf(acc[6] * rden + b1v.z, 0.f);
    o[7] = fmaxf(acc[7] * rden + b1v.w, 0.f);
    // pooling dots: reduce over the 16 lanes of each group (xor strides < 16)
    const float4* wap = (const float4*)(w_attn + f0);
    const float4* wmp = (const float4*)(w_mask + f0);
    float4 wa0 = wap[0], wa1 = wap[1], wm0 = wmp[0], wm1 = wmp[1];
    float pa = o[0]*wa0.x + o[1]*wa0.y + o[2]*wa0.z + o[3]*wa0.w +
               o[4]*wa1.x + o[5]*wa1.y + o[6]*wa1.z + o[7]*wa1.w;
    float pm = o[0]*wm0.x + o[1]*wm0.y + o[2]*wm0.z + o[3]*wm0.w +
               o[4]*wm1.x + o[5]*wm1.y + o[6]*wm1.z + o[7]*wm1.w;
#pragma unroll
    for (int off = 1; off < 16; off <<= 1) {
        pa += __shfl_xor(pa, off);
        pm += __shfl_xor(pm, off);
    }
    float attn = pa + b_attn[0];
    float mask = 1.0f / (1.0f + __expf(-(pm + b_mask[0])));
    float w = attn * mask;
    if (eg == 0) {
        float* pp = wh + (size_t)node * 128 + f0;
        float4 o0 = make_float4(o[0] * w, o[1] * w, o[2] * w, o[3] * w);
        float4 o1 = make_float4(o[4] * w, o[5] * w, o[6] * w, o[7] * w);
        *(float4*)(pp)     = o0;
        *(float4*)(pp + 4) = o1;
    }
}

// ---------------- segment-sum pooling + fused final GEMM ----------------
// one block per graph (256 blocks x 128 threads). batch is sorted ascending;
// binary search the [beg,end) row range, column-sum wh, then out[g,:2].
__global__ __launch_bounds__(128) void pool_seg(const float* __restrict__ wh,
                                                const int* __restrict__ batch,
                                                const float* __restrict__ W_out,
                                                const float* __restrict__ b_out,
                                                float* __restrict__ out, int N) {
    int g = blockIdx.x;
    int t = threadIdx.x;
    // first index with batch[i] >= g
    int lo = 0, hi = N;
    while (lo < hi) { int mid = (lo + hi) >> 1; if (batch[mid] < g) lo = mid + 1; else hi = mid; }
    int beg = lo;
    // first index with batch[i] > g
    hi = N;
    while (lo < hi) { int mid = (lo + hi) >> 1; if (batch[mid] <= g) lo = mid + 1; else hi = mid; }
    int end = lo;
    float s = 0.f;
    for (int r = beg; r < end; ++r) s += wh[(size_t)r * 128 + t];
    __shared__ float sm[128];
    sm[t] = s;
    __syncthreads();
    if (t < 2) {
        const float* w = W_out + t * 128;
        float acc = 0.f;
#pragma unroll 4
        for (int f = 0; f < 128; ++f) acc += sm[f] * w[f];
        out[g * 2 + t] = acc + b_out[t];
    }
}

extern "C" void kernel_launch(void* const* d_in, const int* in_sizes, int n_in,
                              void* d_out, int out_size, void* d_ws, size_t ws_size,
                              hipStream_t stream) {
    const float* x        = (const float*)d_in[0];
    const int* edge_index = (const int*)d_in[1];
    const int* batch      = (const int*)d_in[2];
    const float* W1       = (const float*)d_in[3];
    const float* att_src1 = (const float*)d_in[4];
    const float* att_dst1 = (const float*)d_in[5];
    const float* b1       = (const float*)d_in[6];
    const float* W2       = (const float*)d_in[7];
    const float* att_src2 = (const float*)d_in[8];
    const float* att_dst2 = (const float*)d_in[9];
    const float* b2       = (const float*)d_in[10];
    const float* w_attn   = (const float*)d_in[11];
    const float* b_attn   = (const float*)d_in[12];
    const float* w_mask   = (const float*)d_in[13];
    const float* b_mask   = (const float*)d_in[14];
    const float* W_out    = (const float*)d_in[15];
    const float* b_out    = (const float*)d_in[16];
    float* out = (float*)d_out;

    int N = in_sizes[0] / 128;
    int E = in_sizes[1] / 2;
    const int* esrc = edge_index;
    const int* edst = edge_index + E;

    char* ws = (char*)d_ws;
    size_t off = 0;
    auto alloc = [&](size_t bytes) {
        void* p = ws + off;
        off = (off + bytes + 255) & ~(size_t)255;
        return p;
    };
    ushort* xb       = (ushort*)alloc((size_t)N * 128 * 2);    // bf16 x
    ushort* ax       = (ushort*)alloc((size_t)N * 1024 * 2);   // [N,8,128] bf16
    ushort* r1       = (ushort*)alloc((size_t)N * 512 * 2);    // bf16
    ushort* h2       = (ushort*)alloc((size_t)N * 128 * 2);    // bf16
    float*  wh       = (float*)alloc((size_t)N * 128 * 4);     // weighted h (fp32)
    ushort* w1b      = (ushort*)alloc((size_t)512 * 128 * 2);
    ushort* w2b      = (ushort*)alloc((size_t)128 * 512 * 2);
    float*  v_s      = (float*)alloc((size_t)8 * 128 * 4);
    float*  v_d      = (float*)alloc((size_t)8 * 128 * 4);
    float*  a1s      = (float*)alloc((size_t)N * 8 * 4);
    float*  a1d      = (float*)alloc((size_t)N * 8 * 4);
    float*  a2s      = (float*)alloc((size_t)N * 4);
    float*  a2d      = (float*)alloc((size_t)N * 4);
    int*    row_start= (int*)alloc((size_t)(N + 1) * 4);
    int*    cursor   = (int*)alloc((size_t)N * 4);
    int*    srcs     = (int*)alloc((size_t)E * 4);
    int*    dsts     = (int*)alloc((size_t)E * 4);
    float*  ex1      = (float*)alloc((size_t)E * 8 * 4);
    float*  ex2      = (float*)alloc((size_t)E * 4);

    hipMemsetAsync(cursor, 0, (size_t)N * 4, stream);

    dim3 b256(256);
    // converts + score-vector prep
    int nx4 = N * 128 / 4;
    cvt_bf16<<<(nx4 + 255) / 256, b256, 0, stream>>>(x, xb, nx4);
    cvt_bf16<<<(512 * 128 / 4 + 255) / 256, b256, 0, stream>>>(W1, w1b, 512 * 128 / 4);
    cvt_bf16<<<(128 * 512 / 4 + 255) / 256, b256, 0, stream>>>(W2, w2b, 128 * 512 / 4);
    prep_v<<<4, b256, 0, stream>>>(W1, att_src1, att_dst1, v_s, v_d);
    scoresA<<<(N + 3) / 4, b256, 0, stream>>>(xb, v_s, v_d, a1s, a1d, N);
    // CSR build
    count_edges<<<(E + 255) / 256, b256, 0, stream>>>(edst, cursor, E);
    scan_offsets<<<1, 1024, 0, stream>>>(cursor, row_start, cursor, N);
    fill_edges<<<(E + 255) / 256, b256, 0, stream>>>(esrc, edst, cursor, srcs, dsts, E);
    // layer 1
    exp_edges1<<<(E + 255) / 256, b256, 0, stream>>>(srcs, dsts, a1s, a1d, ex1, E);
    agg_x<<<N, b256, 0, stream>>>(xb, a1s, a1d, row_start, srcs, ex1, ax, N);
    gemm_grouped<<<dim3((N + 127) / 128, 4), b256, 0, stream>>>(ax, w1b, b1, r1, N);
    // layer 2
    gemm_mfma<<<dim3((N + 127) / 128, 1), b256, 0, stream>>>(r1, w2b, h2, N, 128, 512);
    scores2<<<(N + 3) / 4, b256, 0, stream>>>(h2, att_src2, att_dst2, a2s, a2d, N);
    exp_edges2<<<(E + 255) / 256, b256, 0, stream>>>(srcs, dsts, a2s, a2d, ex2, E);
    agg2<<<(N + 3) / 4, b256, 0, stream>>>(h2, a2s, a2d, row_start, srcs, ex2, b2,
                                           w_attn, b_attn, w_mask, b_mask, wh, N);
    // pooling + head (batch sorted -> segment sum, no atomics; final GEMM fused)
    pool_seg<<<256, 128, 0, stream>>>(wh, batch, W_out, b_out, out, N);
}

// Round 9
// 323.991 us; speedup vs baseline: 1.7510x; 1.0379x over previous
//
#include <hip/hip_runtime.h>
#include <math.h>

// R8: agg_x was VALU-issue-bound (62% VALUBusy, 8x inst overhead per useful FMA).
//   - feature-sliced agg_x: wave = 32-feature slice, lane = 2 feats x 8 heads;
//     x kept fp32 (no unpack8, x->bf16 convert deleted); den hoisted to den1 kernel.
//   - single-block scan_offsets -> 3-phase parallel scan (p1 reduce, p2 scan
//     partials, p3 local scan + offset).
//   - W1/W2 bf16 converts fused into one launch.
// agg2/pool_seg (R7, atomic-free) unchanged.

#define NEG_SLOPE 0.2f

using bf16x8 = __attribute__((ext_vector_type(8))) __bf16;
using f32x4  = __attribute__((ext_vector_type(4))) float;

// ---------- bf16 helpers ----------
__device__ __forceinline__ ushort f2bf(float f) {
    unsigned u = __float_as_uint(f);
    unsigned r = (u + 0x7FFFu + ((u >> 16) & 1u)) >> 16;   // RNE
    return (ushort)r;
}
__device__ __forceinline__ unsigned pack2(float a, float b) {
    return (unsigned)f2bf(a) | ((unsigned)f2bf(b) << 16);
}
__device__ __forceinline__ void unpack8(uint4 u, float* f) {
    f[0] = __uint_as_float(u.x << 16); f[1] = __uint_as_float(u.x & 0xFFFF0000u);
    f[2] = __uint_as_float(u.y << 16); f[3] = __uint_as_float(u.y & 0xFFFF0000u);
    f[4] = __uint_as_float(u.z << 16); f[5] = __uint_as_float(u.z & 0xFFFF0000u);
    f[6] = __uint_as_float(u.w << 16); f[7] = __uint_as_float(u.w & 0xFFFF0000u);
}

__device__ __forceinline__ float leaky(float e) {
    return e > 0.f ? e : NEG_SLOPE * e;
}

// ---------------- W1+W2 -> bf16, one launch ----------------
__global__ __launch_bounds__(256) void cvt_w(const float* __restrict__ W1,
                                             const float* __restrict__ W2,
                                             ushort* __restrict__ w1b,
                                             ushort* __restrict__ w2b) {
    int i = blockIdx.x * 256 + threadIdx.x;   // 32768 threads, 4 floats each
    const float* src;
    ushort* dst;
    int j;
    if (i < 16384) { src = W1; dst = w1b; j = i; }
    else           { src = W2; dst = w2b; j = i - 16384; }
    float4 v = ((const float4*)src)[j];
    uint2 o;
    o.x = pack2(v.x, v.y);
    o.y = pack2(v.z, v.w);
    ((uint2*)dst)[j] = o;
}

// ---------------- prep: v_s/v_d[h,f] = sum_c att[h,c] * W1[h*64+c, f] ----------
__global__ __launch_bounds__(256) void prep_v(const float* __restrict__ W1,
                                              const float* __restrict__ att_s,
                                              const float* __restrict__ att_d,
                                              float* __restrict__ v_s,
                                              float* __restrict__ v_d) {
    int tid = blockIdx.x * 256 + threadIdx.x;   // 1024 total
    int h = tid >> 7, f = tid & 127;
    float as = 0.f, ad = 0.f;
    for (int c = 0; c < 64; ++c) {
        float w = W1[(size_t)(h * 64 + c) * 128 + f];
        as += att_s[h * 64 + c] * w;
        ad += att_d[h * 64 + c] * w;
    }
    v_s[tid] = as;
    v_d[tid] = ad;
}

// ---------------- layer-1 scores from fp32 x: a1s/a1d [N,8] ----------------
__global__ __launch_bounds__(256) void scoresA(const float* __restrict__ x,
                                               const float* __restrict__ v_s,
                                               const float* __restrict__ v_d,
                                               float* __restrict__ a1s,
                                               float* __restrict__ a1d, int N) {
    int node = blockIdx.x * 4 + (threadIdx.x >> 6);
    if (node >= N) return;
    int lane = threadIdx.x & 63;
    int head = lane >> 3, f0 = (lane & 7) * 16;
    const float4* xp = (const float4*)(x + (size_t)node * 128 + f0);
    const float4* sp = (const float4*)(v_s + head * 128 + f0);
    const float4* dp = (const float4*)(v_d + head * 128 + f0);
    float ps = 0.f, pd = 0.f;
#pragma unroll
    for (int q = 0; q < 4; ++q) {
        float4 xv = xp[q], s4 = sp[q], d4 = dp[q];
        ps += xv.x * s4.x + xv.y * s4.y + xv.z * s4.z + xv.w * s4.w;
        pd += xv.x * d4.x + xv.y * d4.y + xv.z * d4.z + xv.w * d4.w;
    }
#pragma unroll
    for (int off = 1; off < 8; off <<= 1) {
        ps += __shfl_xor(ps, off);
        pd += __shfl_xor(pd, off);
    }
    if ((lane & 7) == 0) {
        a1s[node * 8 + head] = ps;
        a1d[node * 8 + head] = pd;
    }
}

// ---------------- CSR build ----------------
__global__ void count_edges(const int* __restrict__ dst, int* cnt, int E) {
    int e = blockIdx.x * 256 + threadIdx.x;
    if (e < E) atomicAdd(&cnt[dst[e]], 1);
}

// 3-phase parallel exclusive scan over cnt[0..N)
__global__ __launch_bounds__(128) void scan_p1(const int* __restrict__ cnt,
                                               int* __restrict__ partial, int N) {
    int i = blockIdx.x * 128 + threadIdx.x;
    int v = (i < N) ? cnt[i] : 0;
#pragma unroll
    for (int off = 1; off < 64; off <<= 1) v += __shfl_xor(v, off);
    __shared__ int sm[2];
    if ((threadIdx.x & 63) == 0) sm[threadIdx.x >> 6] = v;
    __syncthreads();
    if (threadIdx.x == 0) partial[blockIdx.x] = sm[0] + sm[1];
}

__global__ __launch_bounds__(256) void scan_p2(int* __restrict__ partial,
                                               int* __restrict__ row_start,
                                               int nb, int N, int E) {
    __shared__ int sm[256];
    int t = threadIdx.x;
    int v = (t < nb) ? partial[t] : 0;
    sm[t] = v;
    __syncthreads();
    for (int off = 1; off < 256; off <<= 1) {
        int add = (t >= off) ? sm[t - off] : 0;
        __syncthreads();
        sm[t] += add;
        __syncthreads();
    }
    if (t < nb) partial[t] = sm[t] - v;   // exclusive prefix of block sums
    if (t == 0) row_start[N] = E;
}

__global__ __launch_bounds__(128) void scan_p3(const int* __restrict__ cnt,
                                               const int* __restrict__ partial,
                                               int* __restrict__ row_start,
                                               int* __restrict__ cursor, int N) {
    __shared__ int sm[128];
    int i = blockIdx.x * 128 + threadIdx.x;
    int t = threadIdx.x;
    int v = (i < N) ? cnt[i] : 0;
    sm[t] = v;
    __syncthreads();
    for (int off = 1; off < 128; off <<= 1) {
        int add = (t >= off) ? sm[t - off] : 0;
        __syncthreads();
        sm[t] += add;
        __syncthreads();
    }
    if (i < N) {
        int start = partial[blockIdx.x] + sm[t] - v;   // exclusive
        row_start[i] = start;
        cursor[i] = start;      // cnt aliases cursor: own-slot read happened above
    }
}

__global__ void fill_edges(const int* __restrict__ src, const int* __restrict__ dst,
                           int* cursor, int* __restrict__ srcs,
                           int* __restrict__ dsts, int E) {
    int e = blockIdx.x * 256 + threadIdx.x;
    if (e < E) {
        int d = dst[e];
        int pos = atomicAdd(&cursor[d], 1);
        srcs[pos] = src[e];
        dsts[pos] = d;
    }
}

// ---------------- per-edge exp, layer 1: ex1[p,8] ----------------
__global__ __launch_bounds__(256) void exp_edges1(const int* __restrict__ srcs,
                                                  const int* __restrict__ dsts,
                                                  const float* __restrict__ a1s,
                                                  const float* __restrict__ a1d,
                                                  float* __restrict__ ex1, int E) {
    int p = blockIdx.x * 256 + threadIdx.x;
    if (p >= E) return;
    int s = srcs[p], d = dsts[p];
    const float4* sp = (const float4*)(a1s + s * 8);
    const float4* dp = (const float4*)(a1d + d * 8);
    float4 s0 = sp[0], s1 = sp[1], d0 = dp[0], d1 = dp[1];
    float4 o0, o1;
    o0.x = __expf(leaky(s0.x + d0.x));
    o0.y = __expf(leaky(s0.y + d0.y));
    o0.z = __expf(leaky(s0.z + d0.z));
    o0.w = __expf(leaky(s0.w + d0.w));
    o1.x = __expf(leaky(s1.x + d1.x));
    o1.y = __expf(leaky(s1.y + d1.y));
    o1.z = __expf(leaky(s1.z + d1.z));
    o1.w = __expf(leaky(s1.w + d1.w));
    float4* op = (float4*)(ex1 + (size_t)p * 8);
    op[0] = o0; op[1] = o1;
}

// ---------------- per-edge exp, layer 2: ex2[p] ----------------
__global__ __launch_bounds__(256) void exp_edges2(const int* __restrict__ srcs,
                                                  const int* __restrict__ dsts,
                                                  const float* __restrict__ a2s,
                                                  const float* __restrict__ a2d,
                                                  float* __restrict__ ex2, int E) {
    int p = blockIdx.x * 256 + threadIdx.x;
    if (p >= E) return;
    ex2[p] = __expf(leaky(a2s[srcs[p]] + a2d[dsts[p]]));
}

// ---------------- den1[n,h] = sum_p ex1[p,h] + ex_self ----------------
// wave per node: 8 edge-streams (s) x 8 heads (h); coalesced ex1 row reads.
__global__ __launch_bounds__(256) void den1_kernel(const float* __restrict__ ex1,
                                                   const float* __restrict__ a1s,
                                                   const float* __restrict__ a1d,
                                                   const int* __restrict__ row_start,
                                                   float* __restrict__ den, int N) {
    int node = blockIdx.x * 4 + (threadIdx.x >> 6);
    if (node >= N) return;
    int lane = threadIdx.x & 63;
    int s = lane >> 3, h = lane & 7;
    int pbeg = row_start[node], pend = row_start[node + 1];
    float d = 0.f;
    for (int p = pbeg + s; p < pend; p += 8) d += ex1[(size_t)p * 8 + h];
    d += __shfl_xor(d, 8);
    d += __shfl_xor(d, 16);
    d += __shfl_xor(d, 32);
    if (s == 0) {
        float e = __expf(leaky(a1s[node * 8 + h] + a1d[node * 8 + h]));
        den[node * 8 + h] = d + e;
    }
}

// ---------------- layer-1 aggregate in x-space: ax[N,8,128] bf16 ----------------
// one block per node; wave w = feature slice [32w, 32w+32); lane = 4 edge-streams
// (eg) x 16 lanes (fl), 2 fp32 features per lane. 16 accumulators, no unpack.
__global__ __launch_bounds__(256) void agg_x(const float* __restrict__ x,
                                             const float* __restrict__ a1s,
                                             const float* __restrict__ a1d,
                                             const float* __restrict__ den,
                                             const int* __restrict__ row_start,
                                             const int* __restrict__ srcs,
                                             const float* __restrict__ ex1,
                                             ushort* __restrict__ ax, int N) {
    int node = blockIdx.x;
    if (node >= N) return;
    int w = threadIdx.x >> 6;
    int lane = threadIdx.x & 63;
    int eg = lane >> 4, fl = lane & 15;
    int f = w * 32 + fl * 2;
    int pbeg = row_start[node], pend = row_start[node + 1];
    float acc[8][2] = {};
    for (int p = pbeg + eg; p < pend; p += 4) {
        int s = srcs[p];
        const float4* ep = (const float4*)(ex1 + (size_t)p * 8);
        float4 e0 = ep[0], e1 = ep[1];
        float2 xv = *(const float2*)(x + (size_t)s * 128 + f);
        acc[0][0] += e0.x * xv.x; acc[0][1] += e0.x * xv.y;
        acc[1][0] += e0.y * xv.x; acc[1][1] += e0.y * xv.y;
        acc[2][0] += e0.z * xv.x; acc[2][1] += e0.z * xv.y;
        acc[3][0] += e0.w * xv.x; acc[3][1] += e0.w * xv.y;
        acc[4][0] += e1.x * xv.x; acc[4][1] += e1.x * xv.y;
        acc[5][0] += e1.y * xv.x; acc[5][1] += e1.y * xv.y;
        acc[6][0] += e1.z * xv.x; acc[6][1] += e1.z * xv.y;
        acc[7][0] += e1.w * xv.x; acc[7][1] += e1.w * xv.y;
    }
#pragma unroll
    for (int h = 0; h < 8; ++h) {
#pragma unroll
        for (int j = 0; j < 2; ++j) {
            acc[h][j] += __shfl_xor(acc[h][j], 16);
            acc[h][j] += __shfl_xor(acc[h][j], 32);
        }
    }
    if (eg == 0) {
        // self loop + normalize + store (lanes 0..15 hold folded totals)
        const float4* sp = (const float4*)(a1s + node * 8);
        const float4* dp = (const float4*)(a1d + node * 8);
        float4 s0 = sp[0], s1 = sp[1], d0 = dp[0], d1 = dp[1];
        float es[8];
        es[0] = __expf(leaky(s0.x + d0.x));
        es[1] = __expf(leaky(s0.y + d0.y));
        es[2] = __expf(leaky(s0.z + d0.z));
        es[3] = __expf(leaky(s0.w + d0.w));
        es[4] = __expf(leaky(s1.x + d1.x));
        es[5] = __expf(leaky(s1.y + d1.y));
        es[6] = __expf(leaky(s1.z + d1.z));
        es[7] = __expf(leaky(s1.w + d1.w));
        float2 xv = *(const float2*)(x + (size_t)node * 128 + f);
        const float4* dnp = (const float4*)(den + node * 8);
        float4 dn0 = dnp[0], dn1 = dnp[1];
        float dn[8] = {dn0.x, dn0.y, dn0.z, dn0.w, dn1.x, dn1.y, dn1.z, dn1.w};
        ushort* base = ax + (size_t)node * 1024 + f;
#pragma unroll
        for (int h = 0; h < 8; ++h) {
            float rden = 1.0f / (dn[h] + 1e-16f);
            float v0 = (acc[h][0] + es[h] * xv.x) * rden;
            float v1 = (acc[h][1] + es[h] * xv.y) * rden;
            *(unsigned*)(base + h * 128) = pack2(v0, v1);
        }
    }
}

// ---------------- grouped GEMM: r1[n, h*64+c] = relu(ax[n,h,:]@W1_h^T + b1) ----
#define LDSB 40
__global__ __launch_bounds__(256) void gemm_grouped(const ushort* __restrict__ AX,
                                                    const ushort* __restrict__ W1b,
                                                    const float* __restrict__ b1,
                                                    ushort* __restrict__ r1,
                                                    int M) {
    __shared__ ushort As[2][128 * LDSB];
    __shared__ ushort Bs[128 * LDSB];
    int t = threadIdx.x;
    int wave = t >> 6, lane = t & 63;
    int quad = lane >> 4, l16 = lane & 15;
    int m0 = blockIdx.x * 128;
    int y = blockIdx.y;                 // cols [128y, 128y+128), heads 2y, 2y+1
    int wm = (wave & 1) * 64;
    int wn = (wave >> 1) * 64;
    int hsel = wn >> 6;
    int srow = t >> 1;
    int sseg = (t & 1) * 16;
    f32x4 acc[4][4] = {};
    for (int k0 = 0; k0 < 128; k0 += 32) {
        uint4 a0v0, a0v1, a1v0, a1v1, bv0, bv1;
        {
            int grow = m0 + srow;
            if (grow < M) {
                const uint4* g0 = (const uint4*)(AX + (size_t)grow * 1024 + (2 * y) * 128 + k0 + sseg);
                const uint4* g1 = (const uint4*)(AX + (size_t)grow * 1024 + (2 * y + 1) * 128 + k0 + sseg);
                a0v0 = g0[0]; a0v1 = g0[1];
                a1v0 = g1[0]; a1v1 = g1[1];
            } else {
                a0v0 = make_uint4(0, 0, 0, 0); a0v1 = a0v0; a1v0 = a0v0; a1v1 = a0v0;
            }
            const uint4* gq = (const uint4*)(W1b + (size_t)(y * 128 + srow) * 128 + k0 + sseg);
            bv0 = gq[0]; bv1 = gq[1];
        }
        __syncthreads();
        *(uint4*)&As[0][srow * LDSB + sseg]     = a0v0;
        *(uint4*)&As[0][srow * LDSB + sseg + 8] = a0v1;
        *(uint4*)&As[1][srow * LDSB + sseg]     = a1v0;
        *(uint4*)&As[1][srow * LDSB + sseg + 8] = a1v1;
        *(uint4*)&Bs[srow * LDSB + sseg]        = bv0;
        *(uint4*)&Bs[srow * LDSB + sseg + 8]    = bv1;
        __syncthreads();
        bf16x8 af[4], bf[4];
#pragma unroll
        for (int i = 0; i < 4; ++i)
            af[i] = *(const bf16x8*)&As[hsel][(wm + i * 16 + l16) * LDSB + quad * 8];
#pragma unroll
        for (int j = 0; j < 4; ++j)
            bf[j] = *(const bf16x8*)&Bs[(wn + j * 16 + l16) * LDSB + quad * 8];
#pragma unroll
        for (int i = 0; i < 4; ++i)
#pragma unroll
            for (int j = 0; j < 4; ++j)
                acc[i][j] = __builtin_amdgcn_mfma_f32_16x16x32_bf16(
                    af[i], bf[j], acc[i][j], 0, 0, 0);
    }
#pragma unroll
    for (int i = 0; i < 4; ++i) {
#pragma unroll
        for (int r = 0; r < 4; ++r) {
            int grow = m0 + wm + i * 16 + quad * 4 + r;
            if (grow < M) {
#pragma unroll
                for (int j = 0; j < 4; ++j) {
                    int gcol = y * 128 + wn + j * 16 + l16;
                    float v = fmaxf(acc[i][j][r] + b1[gcol], 0.f);
                    r1[(size_t)grow * 512 + gcol] = f2bf(v);
                }
            }
        }
    }
}

// ---------------- MFMA GEMM (layer 2): C[M,N] = A[M,K]*B[N,K]^T, bf16 ----------
__global__ __launch_bounds__(256) void gemm_mfma(const ushort* __restrict__ A,
                                                 const ushort* __restrict__ B,
                                                 ushort* __restrict__ C,
                                                 int M, int N, int K) {
    __shared__ ushort As[128 * LDSB];
    __shared__ ushort Bs[128 * LDSB];
    int t = threadIdx.x;
    int wave = t >> 6, lane = t & 63;
    int quad = lane >> 4, l16 = lane & 15;
    int m0 = blockIdx.x * 128;
    int n0 = blockIdx.y * 128;
    int wm = (wave & 1) * 64;
    int wn = (wave >> 1) * 64;
    int srow = t >> 1;
    int sseg = (t & 1) * 16;
    f32x4 acc[4][4] = {};
    for (int k0 = 0; k0 < K; k0 += 32) {
        uint4 av0, av1, bv0, bv1;
        {
            int grow = m0 + srow;
            if (grow < M) {
                const uint4* gp = (const uint4*)(A + (size_t)grow * K + k0 + sseg);
                av0 = gp[0]; av1 = gp[1];
            } else {
                av0 = make_uint4(0, 0, 0, 0); av1 = av0;
            }
            const uint4* gq = (const uint4*)(B + (size_t)(n0 + srow) * K + k0 + sseg);
            bv0 = gq[0]; bv1 = gq[1];
        }
        __syncthreads();
        *(uint4*)&As[srow * LDSB + sseg]     = av0;
        *(uint4*)&As[srow * LDSB + sseg + 8] = av1;
        *(uint4*)&Bs[srow * LDSB + sseg]     = bv0;
        *(uint4*)&Bs[srow * LDSB + sseg + 8] = bv1;
        __syncthreads();
        bf16x8 af[4], bf[4];
#pragma unroll
        for (int i = 0; i < 4; ++i)
            af[i] = *(const bf16x8*)&As[(wm + i * 16 + l16) * LDSB + quad * 8];
#pragma unroll
        for (int j = 0; j < 4; ++j)
            bf[j] = *(const bf16x8*)&Bs[(wn + j * 16 + l16) * LDSB + quad * 8];
#pragma unroll
        for (int i = 0; i < 4; ++i)
#pragma unroll
            for (int j = 0; j < 4; ++j)
                acc[i][j] = __builtin_amdgcn_mfma_f32_16x16x32_bf16(
                    af[i], bf[j], acc[i][j], 0, 0, 0);
    }
#pragma unroll
    for (int i = 0; i < 4; ++i) {
#pragma unroll
        for (int r = 0; r < 4; ++r) {
            int grow = m0 + wm + i * 16 + quad * 4 + r;
            if (grow < M) {
#pragma unroll
                for (int j = 0; j < 4; ++j) {
                    int gcol = n0 + wn + j * 16 + l16;
                    C[(size_t)grow * N + gcol] = f2bf(acc[i][j][r]);
                }
            }
        }
    }
}

// ---------------- layer-2 scores ----------------
__global__ __launch_bounds__(256) void scores2(const ushort* __restrict__ h2,
                                               const float* __restrict__ att_s,
                                               const float* __restrict__ att_d,
                                               float* __restrict__ a2s,
                                               float* __restrict__ a2d, int N) {
    int node = blockIdx.x * 4 + (threadIdx.x >> 6);
    if (node >= N) return;
    int lane = threadIdx.x & 63;
    unsigned u = *(const unsigned*)(h2 + (size_t)node * 128 + lane * 2);
    float h0 = __uint_as_float(u << 16), h1v = __uint_as_float(u & 0xFFFF0000u);
    float2 s = *(const float2*)(att_s + lane * 2);
    float2 d = *(const float2*)(att_d + lane * 2);
    float ps = h0 * s.x + h1v * s.y;
    float pd = h0 * d.x + h1v * d.y;
#pragma unroll
    for (int off = 1; off < 64; off <<= 1) {
        ps += __shfl_xor(ps, off);
        pd += __shfl_xor(pd, off);
    }
    if (lane == 0) { a2s[node] = ps; a2d[node] = pd; }
}

// ---------------- layer-2 aggregate + bias + relu + attention weight ----------
// wave per node; 64 lanes = 4 edge-streams x 16 lanes x 8 features. No atomics.
__global__ __launch_bounds__(256) void agg2(const ushort* __restrict__ h2,
                                            const float* __restrict__ a2s,
                                            const float* __restrict__ a2d,
                                            const int* __restrict__ row_start,
                                            const int* __restrict__ srcs,
                                            const float* __restrict__ ex2,
                                            const float* __restrict__ b2,
                                            const float* __restrict__ w_attn,
                                            const float* __restrict__ b_attn,
                                            const float* __restrict__ w_mask,
                                            const float* __restrict__ b_mask,
                                            float* __restrict__ wh, int N) {
    int node = blockIdx.x * 4 + (threadIdx.x >> 6);
    if (node >= N) return;
    int lane = threadIdx.x & 63;
    int eg = lane >> 4, fl = lane & 15;
    int f0 = fl * 8;
    int pbeg = row_start[node], pend = row_start[node + 1];
    float acc[8] = {};
    float den = 0.f;
    for (int p = pbeg + eg; p < pend; p += 4) {
        int s = srcs[p];
        float ex = ex2[p];
        float v[8];
        unpack8(*(const uint4*)(h2 + (size_t)s * 128 + f0), v);
        den += ex;
#pragma unroll
        for (int j = 0; j < 8; ++j) acc[j] += ex * v[j];
    }
    den += __shfl_xor(den, 16);
    den += __shfl_xor(den, 32);
#pragma unroll
    for (int j = 0; j < 8; ++j) {
        acc[j] += __shfl_xor(acc[j], 16);
        acc[j] += __shfl_xor(acc[j], 32);
    }
    // self loop
    {
        float exs = __expf(leaky(a2s[node] + a2d[node]));
        float q[8];
        unpack8(*(const uint4*)(h2 + (size_t)node * 128 + f0), q);
        den += exs;
#pragma unroll
        for (int j = 0; j < 8; ++j) acc[j] += exs * q[j];
    }
    float rden = 1.0f / (den + 1e-16f);
    const float4* bp = (const float4*)(b2 + f0);
    float4 b0 = bp[0], b1v = bp[1];
    float o[8];
    o[0] = fmaxf(acc[0] * rden + b0.x, 0.f);
    o[1] = fmaxf(acc[1] * rden + b0.y, 0.f);
    o[2] = fmaxf(acc[2] * rden + b0.z, 0.f);
    o[3] = fmaxf(acc[3] * rden + b0.w, 0.f);
    o[4] = fmaxf(acc[4] * rden + b1v.x, 0.f);
    o[5] = fmaxf(acc[5] * rden + b1v.y, 0.f);
    o[6] = fmaxf(acc[6] * rden + b1v.z, 0.f);
    o[7] = fmaxf(acc[7] * rden + b1v.w, 0.f);
    const float4* wap = (const float4*)(w_attn + f0);
    const float4* wmp = (const float4*)(w_mask + f0);
    float4 wa0 = wap[0], wa1 = wap[1], wm0 = wmp[0], wm1 = wmp[1];
    float pa = o[0]*wa0.x + o[1]*wa0.y + o[2]*wa0.z + o[3]*wa0.w +
               o[4]*wa1.x + o[5]*wa1.y + o[6]*wa1.z + o[7]*wa1.w;
    float pm = o[0]*wm0.x + o[1]*wm0.y + o[2]*wm0.z + o[3]*wm0.w +
               o[4]*wm1.x + o[5]*wm1.y + o[6]*wm1.z + o[7]*wm1.w;
#pragma unroll
    for (int off = 1; off < 16; off <<= 1) {
        pa += __shfl_xor(pa, off);
        pm += __shfl_xor(pm, off);
    }
    float attn = pa + b_attn[0];
    float mask = 1.0f / (1.0f + __expf(-(pm + b_mask[0])));
    float w = attn * mask;
    if (eg == 0) {
        float* pp = wh + (size_t)node * 128 + f0;
        *(float4*)(pp)     = make_float4(o[0] * w, o[1] * w, o[2] * w, o[3] * w);
        *(float4*)(pp + 4) = make_float4(o[4] * w, o[5] * w, o[6] * w, o[7] * w);
    }
}

// ---------------- segment-sum pooling + fused final GEMM ----------------
__global__ __launch_bounds__(128) void pool_seg(const float* __restrict__ wh,
                                                const int* __restrict__ batch,
                                                const float* __restrict__ W_out,
                                                const float* __restrict__ b_out,
                                                float* __restrict__ out, int N) {
    int g = blockIdx.x;
    int t = threadIdx.x;
    int lo = 0, hi = N;
    while (lo < hi) { int mid = (lo + hi) >> 1; if (batch[mid] < g) lo = mid + 1; else hi = mid; }
    int beg = lo;
    hi = N;
    while (lo < hi) { int mid = (lo + hi) >> 1; if (batch[mid] <= g) lo = mid + 1; else hi = mid; }
    int end = lo;
    float s = 0.f;
    for (int r = beg; r < end; ++r) s += wh[(size_t)r * 128 + t];
    __shared__ float sm[128];
    sm[t] = s;
    __syncthreads();
    if (t < 2) {
        const float* w = W_out + t * 128;
        float acc = 0.f;
#pragma unroll 4
        for (int f = 0; f < 128; ++f) acc += sm[f] * w[f];
        out[g * 2 + t] = acc + b_out[t];
    }
}

extern "C" void kernel_launch(void* const* d_in, const int* in_sizes, int n_in,
                              void* d_out, int out_size, void* d_ws, size_t ws_size,
                              hipStream_t stream) {
    const float* x        = (const float*)d_in[0];
    const int* edge_index = (const int*)d_in[1];
    const int* batch      = (const int*)d_in[2];
    const float* W1       = (const float*)d_in[3];
    const float* att_src1 = (const float*)d_in[4];
    const float* att_dst1 = (const float*)d_in[5];
    const float* b1       = (const float*)d_in[6];
    const float* W2       = (const float*)d_in[7];
    const float* att_src2 = (const float*)d_in[8];
    const float* att_dst2 = (const float*)d_in[9];
    const float* b2       = (const float*)d_in[10];
    const float* w_attn   = (const float*)d_in[11];
    const float* b_attn   = (const float*)d_in[12];
    const float* w_mask   = (const float*)d_in[13];
    const float* b_mask   = (const float*)d_in[14];
    const float* W_out    = (const float*)d_in[15];
    const float* b_out    = (const float*)d_in[16];
    float* out = (float*)d_out;

    int N = in_sizes[0] / 128;
    int E = in_sizes[1] / 2;
    const int* esrc = edge_index;
    const int* edst = edge_index + E;

    char* ws = (char*)d_ws;
    size_t off = 0;
    auto alloc = [&](size_t bytes) {
        void* p = ws + off;
        off = (off + bytes + 255) & ~(size_t)255;
        return p;
    };
    ushort* ax       = (ushort*)alloc((size_t)N * 1024 * 2);   // [N,8,128] bf16
    ushort* r1       = (ushort*)alloc((size_t)N * 512 * 2);    // bf16
    ushort* h2       = (ushort*)alloc((size_t)N * 128 * 2);    // bf16
    float*  wh       = (float*)alloc((size_t)N * 128 * 4);     // weighted h (fp32)
    ushort* w1b      = (ushort*)alloc((size_t)512 * 128 * 2);
    ushort* w2b      = (ushort*)alloc((size_t)128 * 512 * 2);
    float*  v_s      = (float*)alloc((size_t)8 * 128 * 4);
    float*  v_d      = (float*)alloc((size_t)8 * 128 * 4);
    float*  a1s      = (float*)alloc((size_t)N * 8 * 4);
    float*  a1d      = (float*)alloc((size_t)N * 8 * 4);
    float*  den      = (float*)alloc((size_t)N * 8 * 4);
    float*  a2s      = (float*)alloc((size_t)N * 4);
    float*  a2d      = (float*)alloc((size_t)N * 4);
    int*    row_start= (int*)alloc((size_t)(N + 1) * 4);
    int*    cursor   = (int*)alloc((size_t)N * 4);
    int*    partial  = (int*)alloc((size_t)256 * 4);
    int*    srcs     = (int*)alloc((size_t)E * 4);
    int*    dsts     = (int*)alloc((size_t)E * 4);
    float*  ex1      = (float*)alloc((size_t)E * 8 * 4);
    float*  ex2      = (float*)alloc((size_t)E * 4);

    hipMemsetAsync(cursor, 0, (size_t)N * 4, stream);

    dim3 b256(256);
    int nb = (N + 127) / 128;
    // weight converts + score-vector prep
    cvt_w<<<128, b256, 0, stream>>>(W1, W2, w1b, w2b);
    prep_v<<<4, b256, 0, stream>>>(W1, att_src1, att_dst1, v_s, v_d);
    scoresA<<<(N + 3) / 4, b256, 0, stream>>>(x, v_s, v_d, a1s, a1d, N);
    // CSR build (3-phase parallel scan)
    count_edges<<<(E + 255) / 256, b256, 0, stream>>>(edst, cursor, E);
    scan_p1<<<nb, 128, 0, stream>>>(cursor, partial, N);
    scan_p2<<<1, 256, 0, stream>>>(partial, row_start, nb, N, E);
    scan_p3<<<nb, 128, 0, stream>>>(cursor, partial, row_start, cursor, N);
    fill_edges<<<(E + 255) / 256, b256, 0, stream>>>(esrc, edst, cursor, srcs, dsts, E);
    // layer 1
    exp_edges1<<<(E + 255) / 256, b256, 0, stream>>>(srcs, dsts, a1s, a1d, ex1, E);
    den1_kernel<<<(N + 3) / 4, b256, 0, stream>>>(ex1, a1s, a1d, row_start, den, N);
    agg_x<<<N, b256, 0, stream>>>(x, a1s, a1d, den, row_start, srcs, ex1, ax, N);
    gemm_grouped<<<dim3((N + 127) / 128, 4), b256, 0, stream>>>(ax, w1b, b1, r1, N);
    // layer 2
    gemm_mfma<<<dim3((N + 127) / 128, 1), b256, 0, stream>>>(r1, w2b, h2, N, 128, 512);
    scores2<<<(N + 3) / 4, b256, 0, stream>>>(h2, att_src2, att_dst2, a2s, a2d, N);
    exp_edges2<<<(E + 255) / 256, b256, 0, stream>>>(srcs, dsts, a2s, a2d, ex2, E);
    agg2<<<(N + 3) / 4, b256, 0, stream>>>(h2, a2s, a2d, row_start, srcs, ex2, b2,
                                           w_attn, b_attn, w_mask, b_mask, wh, N);
    // pooling + head
    pool_seg<<<256, 128, 0, stream>>>(wh, batch, W_out, b_out, out, N);
}